// Round 9
// baseline (718.035 us; speedup 1.0000x reference)
//
#include <hip/hip_runtime.h>

// NeuronInteraction: B=32, N=4096, D=256, H=4, hd=64, MSG_K=256, k=256
// Pipeline:
//  fill0 -> topk1(radix-select, DETERMINISTIC index-order compaction) ->
//  prep(bf16 weights + packed W^T) -> gatherX -> qkv GEMM -> attn_k
//  (S+softmax+PV fused, S in LDS) -> msgc_k -> FUSED bf16 MFMA MLP ->
//  selectT -> bandlist -> bandfix -> topk2 -> scatter.
// Top-k via exact threshold selection (not sort): downstream is order-invariant
// in exact arithmetic; fp32 attention reductions iterate in slot order, so the
// slot PERMUTATION must be deterministic for graph-replay reproducibility.
// R8 post-mortem: R7's replay divergence (absmax 0.8 = top-k flip) is best
// explained by topk1's atomicAdd slot ordering varying across replays -> ulp
// shifts in attention fp32 sums -> na shifts ~1e-7 -> rank-256 tie flips.
// attn_k's barrier audit is clean (twice). R9: (a) topk1 compaction via
// index-ordered prefix sums (packed 2-counter shfl_up scan) -> fully
// deterministic pipeline; (b) re-land attn_k (saves ~40us + Sb buffer).
// BAND_EPS=0.004: bf16-path na error max-stat ~1.1e-4 (36x margin).

constexpr int KC = 32;
constexpr int CMAX = 2304;           // E[cands]=2012, sigma~32 -> +9 sigma
constexpr float BAND_EPS = 0.004f;
constexpr int MAXBAND = 512;         // E[band]~47 -> 10x margin

typedef short bf16x8 __attribute__((ext_vector_type(8)));
typedef float f32x4 __attribute__((ext_vector_type(4)));

__device__ __forceinline__ float gelu_f(float x) {
    return 0.5f * x * (1.0f + erff(x * 0.70710678118654752440f));
}
__device__ __forceinline__ unsigned short f2bf(float f) {
    unsigned u = __float_as_uint(f);
    return (unsigned short)((u + 0x7fffu + ((u >> 16) & 1u)) >> 16);
}
__device__ __forceinline__ float bf2f(unsigned short h) {
    return __uint_as_float(((unsigned)h) << 16);
}
// XOR swizzle for a [R][256] bf16 LDS tile (row stride 512B): spreads the
// 16B granules of 8 consecutive rows across distinct banks so that
// ds_read_b128 of {rows r..r+15, same col-chunk} is ~2-way (free, m136).
__device__ __forceinline__ int swz(int row, int byteInRow) {
    return (row << 9) + (byteInRow ^ ((row & 7) << 4));
}

// ---------------- zero-fill output ----------------
__global__ void __launch_bounds__(256) fill0_k(float4* p, long n4) {
    long i = (long)blockIdx.x * 256 + threadIdx.x;
    long stride = (long)gridDim.x * 256;
    float4 z = make_float4(0.f, 0.f, 0.f, 0.f);
    for (; i < n4; i += stride) p[i] = z;
}

// ---------------- top-k #1: radix threshold + DETERMINISTIC compaction ------
// Slots assigned in ascending element-index order via prefix-sum compaction
// (no atomics) so the candidate permutation is a pure function of the data.
__global__ void __launch_bounds__(256) topk1_k(const float* __restrict__ act,
        float* __restrict__ svals, int* __restrict__ sidx, int* __restrict__ cnt)
{
    __shared__ int cs[4];
    int b = blockIdx.x, tid = threadIdx.x;
    int wid = tid >> 6, lane = tid & 63;
    unsigned v[16];
    #pragma unroll
    for (int s = 0; s < 16; ++s)
        v[s] = __float_as_uint(act[b * 4096 + s * 256 + tid]); // >=0: bits monotone

    auto reduce4 = [&](int c) -> int {
        #pragma unroll
        for (int off = 32; off >= 1; off >>= 1) c += __shfl_xor(c, off);
        if (lane == 0) cs[wid] = c;
        __syncthreads();
        int tot = cs[0] + cs[1] + cs[2] + cs[3];
        __syncthreads();
        return tot;
    };
    auto countGE = [&](unsigned thr) -> int {
        int c = 0;
        #pragma unroll
        for (int s = 0; s < 16; ++s) c += (v[s] >= thr) ? 1 : 0;
        return reduce4(c);
    };
    auto countEqLt = [&](unsigned vs, int icut) -> int {
        int c = 0;
        #pragma unroll
        for (int s = 0; s < 16; ++s)
            c += (v[s] == vs && (s * 256 + tid) < icut) ? 1 : 0;
        return reduce4(c);
    };

    unsigned vstar = 0;
    for (int bit = 31; bit >= 0; --bit) {
        unsigned cand = vstar | (1u << bit);
        if (countGE(cand) >= 256) vstar = cand;
    }
    int cgt = countGE(vstar + 1);
    int needed = 256 - cgt;
    int icut = 4096;
    if (countEqLt(vstar, 4096) > needed) {
        int lo = 0, hi = 4096;
        for (int it = 0; it < 12; ++it) {
            int mid = (lo + hi) >> 1;
            if (countEqLt(vstar, mid) <= needed) lo = mid; else hi = mid;
        }
        icut = lo;
    }
    // ---- deterministic compaction: packed {top, rest} prefix sums ----
    // (entering here barrier-synced: reduce4 ends with __syncthreads)
    float th = __uint_as_float(vstar) - 0.4288f;  // > 3/7 margin
    int basePacked = 0;   // low 16: top base, high 16: rest base (uniform)
    for (int s = 0; s < 16; ++s) {
        int i = s * 256 + tid;
        unsigned vb = v[s];
        float f = __uint_as_float(vb);
        bool top = (vb > vstar) || (vb == vstar && i < icut);
        bool rest = (!top) && (f >= th);
        int flag = (top ? 1 : 0) | (rest ? (1 << 16) : 0);
        int x = flag;
        #pragma unroll
        for (int off = 1; off < 64; off <<= 1) {   // inclusive scan in wave
            int n = __shfl_up(x, off);
            if (lane >= off) x += n;
        }
        if (lane == 63) cs[wid] = x;
        __syncthreads();
        int waveOff = 0;
        #pragma unroll
        for (int w = 0; w < 4; ++w) if (w < wid) waveOff += cs[w];
        int tot = cs[0] + cs[1] + cs[2] + cs[3];
        int excl = x - flag + waveOff;             // exclusive prefix (packed)
        if (top) {
            int slot = (basePacked & 0xffff) + (excl & 0xffff);
            sidx[b * 4096 + slot] = i;
            svals[b * 4096 + slot] = f;
        } else if (rest) {
            int slot = 256 + (basePacked >> 16) + (excl >> 16);
            if (slot < CMAX) {
                sidx[b * 4096 + slot] = i;
                svals[b * 4096 + slot] = f;
            }
        }
        basePacked += tot;
        __syncthreads();   // protect cs reuse next round
    }
    if (tid == 0) cnt[b] = min(256 + (basePacked >> 16), CMAX);
}

// ---------------- top-k #2: radix threshold selection over candidates --------
// (atomic slot order is fine here: each output entry depends only on itself)
__global__ void __launch_bounds__(256) topk2_k(const float* __restrict__ newact,
        const int* __restrict__ sidx, const int* __restrict__ cnt,
        float* __restrict__ selv, int* __restrict__ selo, int* __restrict__ selp)
{
    __shared__ int cs[4];
    __shared__ int sSel;
    int b = blockIdx.x, tid = threadIdx.x;
    int wid = tid >> 6, lane = tid & 63;
    int C = min(cnt[b], CMAX);
    unsigned v[9];
    int org[9];
    #pragma unroll
    for (int s = 0; s < 9; ++s) {
        int p = s * 256 + tid;
        bool ok = (p < C && p < CMAX);
        v[s] = ok ? __float_as_uint(newact[(long)b * CMAX + p]) : 0u;
        org[s] = ok ? sidx[b * 4096 + p] : 0x7FFFFFFF;
    }
    auto reduce4 = [&](int c) -> int {
        #pragma unroll
        for (int off = 32; off >= 1; off >>= 1) c += __shfl_xor(c, off);
        if (lane == 0) cs[wid] = c;
        __syncthreads();
        int tot = cs[0] + cs[1] + cs[2] + cs[3];
        __syncthreads();
        return tot;
    };
    auto countGE = [&](unsigned thr) -> int {
        int c = 0;
        #pragma unroll
        for (int s = 0; s < 9; ++s) c += (v[s] >= thr) ? 1 : 0;
        return reduce4(c);
    };
    auto countEqLt = [&](unsigned vs, int icut) -> int {
        int c = 0;
        #pragma unroll
        for (int s = 0; s < 9; ++s) c += (v[s] == vs && org[s] < icut) ? 1 : 0;
        return reduce4(c);
    };

    unsigned vstar = 0;
    for (int bit = 31; bit >= 0; --bit) {
        unsigned cand = vstar | (1u << bit);
        if (countGE(cand) >= 256) vstar = cand;
    }
    int cgt = countGE(vstar + 1);
    int needed = 256 - cgt;
    int icut = 4096;
    if (countEqLt(vstar, 4096) > needed) {
        int lo = 0, hi = 4096;
        for (int it = 0; it < 12; ++it) {
            int mid = (lo + hi) >> 1;
            if (countEqLt(vstar, mid) <= needed) lo = mid; else hi = mid;
        }
        icut = lo;
    }
    if (tid == 0) sSel = 0;
    __syncthreads();
    #pragma unroll
    for (int s = 0; s < 9; ++s) {
        unsigned vb = v[s];
        bool sel = (vb > vstar) || (vb == vstar && org[s] < icut);
        if (sel) {
            int slot = atomicAdd(&sSel, 1);
            selv[b * 256 + slot] = __uint_as_float(vb);
            selo[b * 256 + slot] = org[s];
            selp[b * 256 + slot] = s * 256 + tid;
        }
    }
}

// ---------------- generic fp32 tiled GEMM (qkv projection) ----------------
// EPI: 0 none, 1 +bias, 2 +bias*rowscale, 3 *cscale
template<int TM, int TN, int RM, int RN, bool BT, bool GATHER, int EPI>
__global__ void __launch_bounds__(256) gemm_k(
    const float* __restrict__ A, int lda, long sA1, long sA2, int divA,
    const float* __restrict__ B, int ldb, long sB1, long sB2, int divB,
    float* __restrict__ C, int ldc, long sC1, long sC2, int divC,
    int K, const float* __restrict__ bias, const float* __restrict__ rowscale,
    long rsStride, const int* __restrict__ gmap, long gmapStride, float cscale)
{
    constexpr int TX = TN / RN, TY = TM / RM;
    static_assert(TX * TY == 256, "block must be 256 threads");
    __shared__ float As[KC][TM + 4];
    __shared__ float Bs[KC][TN + 4];
    int z = blockIdx.z;
    const float* Ab = A + (long)(z / divA) * sA1 + (long)(z % divA) * sA2;
    const float* Bb = B + (long)(z / divB) * sB1 + (long)(z % divB) * sB2;
    float* Cb = C + (long)(z / divC) * sC1 + (long)(z % divC) * sC2;
    int m0 = blockIdx.y * TM, n0 = blockIdx.x * TN;
    int tid = threadIdx.x;
    int tx = tid % TX, ty = tid / TX;
    float acc[RM][RN];
    #pragma unroll
    for (int i = 0; i < RM; ++i)
        #pragma unroll
        for (int j = 0; j < RN; ++j) acc[i][j] = 0.f;

    for (int k0 = 0; k0 < K; k0 += KC) {
        __syncthreads();
        #pragma unroll
        for (int u = 0; u < (TM * KC) / 1024; ++u) {
            int idx = tid + u * 256;
            int m = idx / (KC / 4), k4 = idx % (KC / 4);
            int row = m0 + m;
            long grow = GATHER ? (long)gmap[(long)z * gmapStride + row] : (long)row;
            float4 v = *(const float4*)(Ab + grow * lda + k0 + k4 * 4);
            As[k4 * 4 + 0][m] = v.x; As[k4 * 4 + 1][m] = v.y;
            As[k4 * 4 + 2][m] = v.z; As[k4 * 4 + 3][m] = v.w;
        }
        if (BT) {
            #pragma unroll
            for (int u = 0; u < (TN * KC) / 1024; ++u) {
                int idx = tid + u * 256;
                int n = idx / (KC / 4), k4 = idx % (KC / 4);
                float4 v = *(const float4*)(Bb + (long)(n0 + n) * ldb + k0 + k4 * 4);
                Bs[k4 * 4 + 0][n] = v.x; Bs[k4 * 4 + 1][n] = v.y;
                Bs[k4 * 4 + 2][n] = v.z; Bs[k4 * 4 + 3][n] = v.w;
            }
        } else {
            #pragma unroll
            for (int u = 0; u < (TN * KC) / 1024; ++u) {
                int idx = tid + u * 256;
                int k = idx / (TN / 4), n4 = idx % (TN / 4);
                float4 v = *(const float4*)(Bb + (long)(k0 + k) * ldb + n0 + n4 * 4);
                *(float4*)&Bs[k][n4 * 4] = v;
            }
        }
        __syncthreads();
        #pragma unroll
        for (int k = 0; k < KC; ++k) {
            float av[RM], bv[RN];
            #pragma unroll
            for (int i = 0; i < RM; i += 4) {
                float4 t = *(const float4*)&As[k][ty * RM + i];
                av[i] = t.x; av[i + 1] = t.y; av[i + 2] = t.z; av[i + 3] = t.w;
            }
            #pragma unroll
            for (int j = 0; j < RN; j += 4) {
                float4 t = *(const float4*)&Bs[k][tx * RN + j];
                bv[j] = t.x; bv[j + 1] = t.y; bv[j + 2] = t.z; bv[j + 3] = t.w;
            }
            #pragma unroll
            for (int i = 0; i < RM; ++i)
                #pragma unroll
                for (int j = 0; j < RN; ++j)
                    acc[i][j] = fmaf(av[i], bv[j], acc[i][j]);
        }
    }
    #pragma unroll
    for (int i = 0; i < RM; ++i) {
        int gm = m0 + ty * RM + i;
        float rs = 1.f;
        if (EPI == 2) rs = rowscale[(long)z * rsStride + gm];
        #pragma unroll
        for (int j = 0; j < RN; j += 4) {
            int gn = n0 + tx * RN + j;
            float4 v = make_float4(acc[i][j], acc[i][j + 1], acc[i][j + 2], acc[i][j + 3]);
            if (EPI == 1 || EPI == 2) {
                float4 bb = *(const float4*)(bias + gn);
                v.x += bb.x; v.y += bb.y; v.z += bb.z; v.w += bb.w;
            }
            if (EPI == 2) { v.x *= rs; v.y *= rs; v.z *= rs; v.w *= rs; }
            if (EPI == 3) { v.x *= cscale; v.y *= cscale; v.z *= cscale; v.w *= cscale; }
            *(float4*)(Cb + (long)gm * ldc + gn) = v;
        }
    }
}

// ---------------- fused attention: S=softmax(QK^T/8); O = S@V ----------------
// Block = 32 q-rows of one (b,h); grid (8 qtiles, 4 h, 32 b) = 1024 blocks.
// S tile lives in LDS (never hits global). Staging pattern, fma order, and
// softmax reduction replicate the R6 two-kernel path exactly -> bit-identical
// given the same candidate permutation. LDS 73.5KB -> 2 blocks/CU.
__global__ void __launch_bounds__(256) attn_k(
    const float* __restrict__ qkv, float* __restrict__ Ob)
{
    __shared__ float As[32][68];    // Q chunk (phase1) / V chunk (phase2)
    __shared__ float Bs[32][260];   // K rows (BT staging)
    __shared__ float Ss[32][260];   // softmaxed scores
    int qt = blockIdx.x, h = blockIdx.y, b = blockIdx.z;
    int tid = threadIdx.x;
    const float* Qb = qkv + (long)b * 196608 + h * 64;
    const float* Kb = Qb + 256;
    const float* Vb = Qb + 512;
    int m0 = qt * 32;

    // ---- phase 1: S rows = softmax(Q K^T * 0.125) ----
    {
        int tx = tid & 31, ty = tid >> 5;        // TM=32 RM=4, TN=256 RN=8
        float acc[4][8];
        #pragma unroll
        for (int i = 0; i < 4; ++i)
            #pragma unroll
            for (int j = 0; j < 8; ++j) acc[i][j] = 0.f;
        for (int k0 = 0; k0 < 64; k0 += 32) {
            __syncthreads();
            {   // stage Q 32x32 (1 float4/thread)
                int m = tid >> 3, k4 = tid & 7;
                float4 v = *(const float4*)(Qb + (long)(m0 + m) * 768 + k0 + k4 * 4);
                As[k4 * 4 + 0][m] = v.x; As[k4 * 4 + 1][m] = v.y;
                As[k4 * 4 + 2][m] = v.z; As[k4 * 4 + 3][m] = v.w;
            }
            #pragma unroll
            for (int u = 0; u < 8; ++u) {   // stage K 256 rows x 32 (BT)
                int idx = tid + u * 256;
                int n = idx >> 3, k4 = idx & 7;
                float4 v = *(const float4*)(Kb + (long)n * 768 + k0 + k4 * 4);
                Bs[k4 * 4 + 0][n] = v.x; Bs[k4 * 4 + 1][n] = v.y;
                Bs[k4 * 4 + 2][n] = v.z; Bs[k4 * 4 + 3][n] = v.w;
            }
            __syncthreads();
            #pragma unroll
            for (int k = 0; k < 32; ++k) {
                float av[4], bv[8];
                float4 ta = *(const float4*)&As[k][ty * 4];
                av[0] = ta.x; av[1] = ta.y; av[2] = ta.z; av[3] = ta.w;
                #pragma unroll
                for (int j = 0; j < 8; j += 4) {
                    float4 t = *(const float4*)&Bs[k][tx * 8 + j];
                    bv[j] = t.x; bv[j + 1] = t.y; bv[j + 2] = t.z; bv[j + 3] = t.w;
                }
                #pragma unroll
                for (int i = 0; i < 4; ++i)
                    #pragma unroll
                    for (int j = 0; j < 8; ++j)
                        acc[i][j] = fmaf(av[i], bv[j], acc[i][j]);
            }
        }
        // row softmax: row held by 32 same-ty threads = one 32-lane half-wave
        #pragma unroll
        for (int i = 0; i < 4; ++i) {
            float m = -1e30f;
            #pragma unroll
            for (int j = 0; j < 8; ++j) {
                acc[i][j] *= 0.125f;
                m = fmaxf(m, acc[i][j]);
            }
            #pragma unroll
            for (int off = 16; off >= 1; off >>= 1) m = fmaxf(m, __shfl_xor(m, off));
            float s = 0.f;
            #pragma unroll
            for (int j = 0; j < 8; ++j) {
                acc[i][j] = expf(acc[i][j] - m);
                s += acc[i][j];
            }
            #pragma unroll
            for (int off = 16; off >= 1; off >>= 1) s += __shfl_xor(s, off);
            float inv = 1.f / s;
            #pragma unroll
            for (int j = 0; j < 8; ++j) acc[i][j] *= inv;
        }
        #pragma unroll
        for (int i = 0; i < 4; ++i)
            #pragma unroll
            for (int j = 0; j < 8; j += 4) {
                float4 v = make_float4(acc[i][j], acc[i][j + 1],
                                       acc[i][j + 2], acc[i][j + 3]);
                *(float4*)&Ss[ty * 4 + i][tx * 8 + j] = v;
            }
    }
    // ---- phase 2: O = S @ V ----
    {
        int tx = tid & 15, ty = tid >> 4;    // TM=32 RM=2, TN=64 RN=4
        float acc[2][4];
        #pragma unroll
        for (int i = 0; i < 2; ++i)
            #pragma unroll
            for (int j = 0; j < 4; ++j) acc[i][j] = 0.f;
        for (int k0 = 0; k0 < 256; k0 += 32) {
            __syncthreads();   // Ss ready (1st iter) + As reuse safe
            #pragma unroll
            for (int u = 0; u < 2; ++u) {    // stage V 32 rows x 64 cols
                int idx = tid + u * 256;
                int k = idx >> 4, n4 = idx & 15;
                float4 v = *(const float4*)(Vb + (long)(k0 + k) * 768 + n4 * 4);
                *(float4*)&As[k][n4 * 4] = v;
            }
            __syncthreads();
            #pragma unroll
            for (int k = 0; k < 32; ++k) {
                float av[2], bv[4];
                av[0] = Ss[ty * 2 + 0][k0 + k];
                av[1] = Ss[ty * 2 + 1][k0 + k];
                float4 t = *(const float4*)&As[k][tx * 4];
                bv[0] = t.x; bv[1] = t.y; bv[2] = t.z; bv[3] = t.w;
                #pragma unroll
                for (int i = 0; i < 2; ++i)
                    #pragma unroll
                    for (int j = 0; j < 4; ++j)
                        acc[i][j] = fmaf(av[i], bv[j], acc[i][j]);
            }
        }
        float* Cb = Ob + (long)b * 65536 + h * 64;
        #pragma unroll
        for (int i = 0; i < 2; ++i) {
            int gm = m0 + ty * 2 + i;
            float4 v = make_float4(acc[i][0], acc[i][1], acc[i][2], acc[i][3]);
            *(float4*)(Cb + (long)gm * 256 + tx * 4) = v;
        }
    }
}

// ---------------- fused: MSGC = ((O@wo^T+bo)*tv) @ W1b^T ---------
// Block = 32 MSG rows x 256 cols; MSG tile lives in LDS (never hits global).
__global__ void __launch_bounds__(256) msgc_k(
    const float* __restrict__ Ob,     // [32][256][256]
    const float* __restrict__ wo,     // [256][256]
    const float* __restrict__ bo,     // [256]
    const float* __restrict__ su_w1,  // [256][512]; cols 256.. = W1b
    const float* __restrict__ svals,  // tv = svals[b*4096 + row]
    float* __restrict__ MSGC)         // [32][256][256]
{
    constexpr int TM = 32, TN = 256, RM = 4, RN = 8;
    constexpr int TX = TN / RN;  // 32
    __shared__ float As[KC][TM + 4];
    __shared__ float Bs[KC][TN + 4];
    __shared__ float Ms[TM][TN + 4];  // MSG tile [m][k]
    int b = blockIdx.y;
    int m0 = blockIdx.x * TM;
    int tid = threadIdx.x;
    int tx = tid % TX, ty = tid / TX;
    const float* Ab = Ob + (long)b * 65536;
    float acc[RM][RN];

    // ---- phase 1: MSG = O @ wo^T + bo, scaled by tv ----
    #pragma unroll
    for (int i = 0; i < RM; ++i)
        #pragma unroll
        for (int j = 0; j < RN; ++j) acc[i][j] = 0.f;
    for (int k0 = 0; k0 < 256; k0 += KC) {
        __syncthreads();
        {   // stage A: 32 rows x KC  (1 float4/thread)
            int m = tid / (KC / 4), k4 = tid % (KC / 4);
            float4 v = *(const float4*)(Ab + (long)(m0 + m) * 256 + k0 + k4 * 4);
            As[k4 * 4 + 0][m] = v.x; As[k4 * 4 + 1][m] = v.y;
            As[k4 * 4 + 2][m] = v.z; As[k4 * 4 + 3][m] = v.w;
        }
        #pragma unroll
        for (int u = 0; u < 8; ++u) {  // stage B (wo, BT): 256 n x KC
            int idx = tid + u * 256;
            int n = idx / (KC / 4), k4 = idx % (KC / 4);
            float4 v = *(const float4*)(wo + (long)n * 256 + k0 + k4 * 4);
            Bs[k4 * 4 + 0][n] = v.x; Bs[k4 * 4 + 1][n] = v.y;
            Bs[k4 * 4 + 2][n] = v.z; Bs[k4 * 4 + 3][n] = v.w;
        }
        __syncthreads();
        #pragma unroll
        for (int k = 0; k < KC; ++k) {
            float av[RM], bv[RN];
            float4 ta = *(const float4*)&As[k][ty * RM];
            av[0] = ta.x; av[1] = ta.y; av[2] = ta.z; av[3] = ta.w;
            #pragma unroll
            for (int j = 0; j < RN; j += 4) {
                float4 t = *(const float4*)&Bs[k][tx * RN + j];
                bv[j] = t.x; bv[j + 1] = t.y; bv[j + 2] = t.z; bv[j + 3] = t.w;
            }
            #pragma unroll
            for (int i = 0; i < RM; ++i)
                #pragma unroll
                for (int j = 0; j < RN; ++j)
                    acc[i][j] = fmaf(av[i], bv[j], acc[i][j]);
        }
    }
    __syncthreads();   // As/Bs reuse below; also orders Ms writes
    #pragma unroll
    for (int i = 0; i < RM; ++i) {
        int gm = m0 + ty * RM + i;
        float tv = svals[b * 4096 + gm];
        #pragma unroll
        for (int j = 0; j < RN; j += 4) {
            int gn = tx * RN + j;
            float4 bb = *(const float4*)(bo + gn);
            float4 v;
            v.x = (acc[i][j + 0] + bb.x) * tv;
            v.y = (acc[i][j + 1] + bb.y) * tv;
            v.z = (acc[i][j + 2] + bb.z) * tv;
            v.w = (acc[i][j + 3] + bb.w) * tv;
            *(float4*)&Ms[ty * RM + i][gn] = v;
        }
    }

    // ---- phase 2: MSGC = MSG @ W1b^T ----
    #pragma unroll
    for (int i = 0; i < RM; ++i)
        #pragma unroll
        for (int j = 0; j < RN; ++j) acc[i][j] = 0.f;
    const float* W1b = su_w1 + 256;
    for (int k0 = 0; k0 < 256; k0 += KC) {
        __syncthreads();
        #pragma unroll
        for (int u = 0; u < 8; ++u) {  // stage B (W1b, BT, ldb=512)
            int idx = tid + u * 256;
            int n = idx / (KC / 4), k4 = idx % (KC / 4);
            float4 v = *(const float4*)(W1b + (long)n * 512 + k0 + k4 * 4);
            Bs[k4 * 4 + 0][n] = v.x; Bs[k4 * 4 + 1][n] = v.y;
            Bs[k4 * 4 + 2][n] = v.z; Bs[k4 * 4 + 3][n] = v.w;
        }
        __syncthreads();
        #pragma unroll
        for (int k = 0; k < KC; ++k) {
            float av[RM], bv[RN];
            #pragma unroll
            for (int i = 0; i < RM; ++i)
                av[i] = Ms[ty * RM + i][k0 + k];   // broadcast reads
            #pragma unroll
            for (int j = 0; j < RN; j += 4) {
                float4 t = *(const float4*)&Bs[k][tx * RN + j];
                bv[j] = t.x; bv[j + 1] = t.y; bv[j + 2] = t.z; bv[j + 3] = t.w;
            }
            #pragma unroll
            for (int i = 0; i < RM; ++i)
                #pragma unroll
                for (int j = 0; j < RN; ++j)
                    acc[i][j] = fmaf(av[i], bv[j], acc[i][j]);
        }
    }
    float* Cb = MSGC + (long)b * 65536;
    #pragma unroll
    for (int i = 0; i < RM; ++i) {
        int gm = m0 + ty * RM + i;
        #pragma unroll
        for (int j = 0; j < RN; j += 4) {
            int gn = tx * RN + j;
            float4 v = make_float4(acc[i][j], acc[i][j + 1], acc[i][j + 2], acc[i][j + 3]);
            *(float4*)(Cb + (long)gm * 256 + gn) = v;
        }
    }
}

// ---------------- prep: bf16 weight conversion + packed fp32 transposes ------
// blocks 0..511: bf16 convert. 512..575: w1P, 576..639: w2P, 640..767: auP.
// Packed layout: dst float4 index (k>>2)*256 + n holds w[k..k+3][n].
__global__ void __launch_bounds__(256) prep_k(
        const float* __restrict__ s1, const float* __restrict__ s2,
        const float* __restrict__ a1,
        unsigned short* __restrict__ o1, unsigned short* __restrict__ o2,
        unsigned short* __restrict__ o3,
        float* __restrict__ w1P, float* __restrict__ w2P, float* __restrict__ auP)
{
    int blk = blockIdx.x, tid = threadIdx.x;
    if (blk < 512) {
        int i = blk * 256 + tid;
        o1[i] = f2bf(s1[i]);
        o3[i] = f2bf(a1[i]);
        if (i < 65536) o2[i] = f2bf(s2[i]);
        return;
    }
    const float* src; float* dst; int ld, ktiles, rel;
    if (blk < 576) { rel = blk - 512; src = s1; ld = 512; dst = w1P; ktiles = 8; }
    else if (blk < 640) { rel = blk - 576; src = s2; ld = 256; dst = w2P; ktiles = 8; }
    else { rel = blk - 640; src = a1; ld = 512; dst = auP; ktiles = 16; }
    int k0 = (rel % ktiles) * 32, n0 = (rel / ktiles) * 32;
    __shared__ float t[32][33];
    int tx = tid & 31, ty = tid >> 5;
    #pragma unroll
    for (int yy = 0; yy < 4; ++yy) {
        int nl = ty * 4 + yy;
        t[nl][tx] = src[(long)(n0 + nl) * ld + k0 + tx];
    }
    __syncthreads();
    #pragma unroll
    for (int yy = 0; yy < 4; ++yy) {
        int k = k0 + ty * 4 + yy;
        dst[(long)(k >> 2) * 1024 + (n0 + tx) * 4 + (k & 3)] = t[tx][ty * 4 + yy];
    }
}

// ---------------- gather candidate rows -> bf16 [B][CMAX][256] ----------------
__global__ void __launch_bounds__(256) gatherX_k(const float* __restrict__ hid,
        const int* __restrict__ sidx, const int* __restrict__ cnt,
        unsigned short* __restrict__ Xb)
{
    int b = blockIdx.y;
    int C = min(cnt[b], CMAX);
    int p = blockIdx.x * 4 + (threadIdx.x >> 6);
    int lane = threadIdx.x & 63;
    unsigned short* dst = Xb + ((long)b * CMAX + p) * 256 + lane * 4;
    if (p < C) {
        int row = sidx[b * 4096 + p];
        float4 v = *(const float4*)(hid + ((long)b * 4096 + row) * 256 + lane * 4);
        ushort4 o; o.x = f2bf(v.x); o.y = f2bf(v.y); o.z = f2bf(v.z); o.w = f2bf(v.w);
        *(ushort4*)dst = o;
    } else {
        ushort4 z; z.x = 0; z.y = 0; z.z = 0; z.w = 0;
        *(ushort4*)dst = z;
    }
}

// ---------------- FUSED bf16 MFMA MLP: su1 -> su2+LN -> au in one kernel -----
// (R4 variant, measured ~153us.) Block = 64 rows x 256 cols, 4 waves.
// X staged once into swizzled LDS (reused stages A+C); H1/NH in 2nd tile.
__global__ void __launch_bounds__(256, 2) fused_mlp_k(
    const unsigned short* __restrict__ Xb,
    const unsigned short* __restrict__ W1,   // [256][512] bf16, K used: 0..255
    const unsigned short* __restrict__ W2,   // [256][256] bf16
    const unsigned short* __restrict__ WA,   // [256][512] bf16, full K
    const float* __restrict__ su_b1v, const float* __restrict__ msgc,
    const float* __restrict__ su_b2v,
    const float* __restrict__ lng, const float* __restrict__ lnb,
    const float* __restrict__ au_b1v,
    const float* __restrict__ w2v, const float* __restrict__ b2s,
    const float* __restrict__ svals, const int* __restrict__ cnt,
    unsigned short* __restrict__ NHb, float* __restrict__ nac)
{
    int b = blockIdx.y;
    int C = min(cnt[b], CMAX);
    int m0 = blockIdx.x * 64;
    if (m0 >= C) return;
    int tid = threadIdx.x;
    int wid = tid >> 6;
    int lane = tid & 63;
    int l15 = lane & 15;
    int q = lane >> 4;
    int n0w = wid * 64;

    __shared__ __align__(16) unsigned short Xs[64 * 256]; // swizzled X tile
    __shared__ __align__(16) unsigned short Hs[64 * 256]; // swizzled H1/NH tile
    __shared__ float rsum[4][64];
    __shared__ float rsq[4][64];
    __shared__ float rmu[64], rrs[64];

    const unsigned short* Ab = Xb + ((long)b * CMAX + m0) * 256;

    #pragma unroll
    for (int rnd = 0; rnd < 8; ++rnd) {
        int idx = rnd * 256 + tid;
        int r = idx >> 5, c = idx & 31;
        bf16x8 v = *(const bf16x8*)(Ab + r * 256 + c * 8);
        *(bf16x8*)((char*)Xs + swz(r, c * 16)) = v;
    }
    __syncthreads();

    f32x4 acc[4][4];

    // ================= stage A: H1 = gelu(X @ W1[:, :256]^T + b1 + msgc) ====
    #pragma unroll
    for (int mt = 0; mt < 4; ++mt)
        #pragma unroll
        for (int nt = 0; nt < 4; ++nt) {
            f32x4 z = {0.f, 0.f, 0.f, 0.f};
            acc[mt][nt] = z;
        }
    {
        const unsigned short* wr[4];
        #pragma unroll
        for (int nt = 0; nt < 4; ++nt) wr[nt] = W1 + (long)(n0w + nt * 16 + l15) * 512;
        #pragma unroll 4
        for (int ks = 0; ks < 8; ++ks) {
            int ko = ks * 32;
            bf16x8 af[4], bfr[4];
            #pragma unroll
            for (int mt = 0; mt < 4; ++mt)
                af[mt] = *(const bf16x8*)((const char*)Xs +
                         swz(mt * 16 + l15, (ko + q * 8) * 2));
            #pragma unroll
            for (int nt = 0; nt < 4; ++nt)
                bfr[nt] = *(const bf16x8*)(wr[nt] + ko + q * 8);
            #pragma unroll
            for (int mt = 0; mt < 4; ++mt)
                #pragma unroll
                for (int nt = 0; nt < 4; ++nt)
                    acc[mt][nt] = __builtin_amdgcn_mfma_f32_16x16x32_bf16(
                        af[mt], bfr[nt], acc[mt][nt], 0, 0, 0);
        }
        float bb[4];
        #pragma unroll
        for (int nt = 0; nt < 4; ++nt) bb[nt] = su_b1v[n0w + nt * 16 + l15];
        #pragma unroll
        for (int mt = 0; mt < 4; ++mt) {
            #pragma unroll
            for (int reg = 0; reg < 4; ++reg) {
                int lr = mt * 16 + q * 4 + reg;
                int p = m0 + lr;
                const float* mrow = msgc + ((long)b * 256 + p) * 256;
                bool hasm = (p < 256);
                #pragma unroll
                for (int nt = 0; nt < 4; ++nt) {
                    int gc = n0w + nt * 16 + l15;
                    float v = acc[mt][nt][reg] + bb[nt];
                    if (hasm) v += mrow[gc];
                    *(unsigned short*)((char*)Hs + swz(lr, gc * 2)) = f2bf(gelu_f(v));
                }
            }
        }
    }
    __syncthreads();

    // ================= stage B: NH = LN(H1 @ W2^T + b2) =====================
    #pragma unroll
    for (int mt = 0; mt < 4; ++mt)
        #pragma unroll
        for (int nt = 0; nt < 4; ++nt) {
            f32x4 z = {0.f, 0.f, 0.f, 0.f};
            acc[mt][nt] = z;
        }
    {
        const unsigned short* wr[4];
        #pragma unroll
        for (int nt = 0; nt < 4; ++nt) wr[nt] = W2 + (long)(n0w + nt * 16 + l15) * 256;
        #pragma unroll
        for (int ks = 0; ks < 8; ++ks) {
            int ko = ks * 32;
            bf16x8 af[4], bfr[4];
            #pragma unroll
            for (int mt = 0; mt < 4; ++mt) {
                int r = mt * 16 + l15;
                af[mt] = *(const bf16x8*)((const char*)Hs + swz(r, (ko + q * 8) * 2));
            }
            #pragma unroll
            for (int nt = 0; nt < 4; ++nt)
                bfr[nt] = *(const bf16x8*)(wr[nt] + ko + q * 8);
            #pragma unroll
            for (int mt = 0; mt < 4; ++mt)
                #pragma unroll
                for (int nt = 0; nt < 4; ++nt)
                    acc[mt][nt] = __builtin_amdgcn_mfma_f32_16x16x32_bf16(
                        af[mt], bfr[nt], acc[mt][nt], 0, 0, 0);
        }
        float bb[4], gg[4], eb[4];
        #pragma unroll
        for (int nt = 0; nt < 4; ++nt) {
            int gc = n0w + nt * 16 + l15;
            bb[nt] = su_b2v[gc]; gg[nt] = lng[gc]; eb[nt] = lnb[gc];
        }
        #pragma unroll
        for (int mt = 0; mt < 4; ++mt)
            #pragma unroll
            for (int nt = 0; nt < 4; ++nt)
                #pragma unroll
                for (int reg = 0; reg < 4; ++reg)
                    acc[mt][nt][reg] += bb[nt];
        #pragma unroll
        for (int mt = 0; mt < 4; ++mt) {
            #pragma unroll
            for (int reg = 0; reg < 4; ++reg) {
                float s = 0.f, s2 = 0.f;
                #pragma unroll
                for (int nt = 0; nt < 4; ++nt) {
                    float v = acc[mt][nt][reg];
                    s += v; s2 += v * v;
                }
                #pragma unroll
                for (int off = 1; off <= 8; off <<= 1) {
                    s += __shfl_xor(s, off);
                    s2 += __shfl_xor(s2, off);
                }
                if (l15 == 0) {
                    int row = mt * 16 + q * 4 + reg;
                    rsum[wid][row] = s; rsq[wid][row] = s2;
                }
            }
        }
        __syncthreads();   // all waves past MFMA loop -> Hs reads complete
        if (tid < 64) {
            float s = rsum[0][tid] + rsum[1][tid] + rsum[2][tid] + rsum[3][tid];
            float s2 = rsq[0][tid] + rsq[1][tid] + rsq[2][tid] + rsq[3][tid];
            float mu = s * (1.f / 256.f);
            float var = s2 * (1.f / 256.f) - mu * mu;
            rmu[tid] = mu;
            rrs[tid] = rsqrtf(var + 1e-5f);
        }
        __syncthreads();
        #pragma unroll
        for (int mt = 0; mt < 4; ++mt) {
            #pragma unroll
            for (int reg = 0; reg < 4; ++reg) {
                int lr = mt * 16 + q * 4 + reg;
                float mu = rmu[lr], rs = rrs[lr];
                #pragma unroll
                for (int nt = 0; nt < 4; ++nt) {
                    int gc = n0w + nt * 16 + l15;
                    unsigned short ov =
                        f2bf((acc[mt][nt][reg] - mu) * rs * gg[nt] + eb[nt]);
                    *(unsigned short*)((char*)Hs + swz(lr, gc * 2)) = ov; // stage C
                }
            }
        }
    }
    __syncthreads();

    // ---- coalesced NH writeback from LDS ----
    #pragma unroll
    for (int rnd = 0; rnd < 8; ++rnd) {
        int idx = rnd * 256 + tid;
        int r = idx >> 5, c = idx & 31;
        bf16x8 v = *(const bf16x8*)((const char*)Hs + swz(r, c * 16));
        *(bf16x8*)(NHb + ((long)b * CMAX + m0 + r) * 256 + c * 8) = v;
    }

    // ================= stage C: au gate over [X, NH] (K=512) ================
    #pragma unroll
    for (int mt = 0; mt < 4; ++mt)
        #pragma unroll
        for (int nt = 0; nt < 4; ++nt) {
            f32x4 z = {0.f, 0.f, 0.f, 0.f};
            acc[mt][nt] = z;
        }
    {
        const unsigned short* wr[4];
        #pragma unroll
        for (int nt = 0; nt < 4; ++nt) wr[nt] = WA + (long)(n0w + nt * 16 + l15) * 512;
        #pragma unroll 4
        for (int ks = 0; ks < 8; ++ks) {         // K 0..255: original X (LDS)
            int ko = ks * 32;
            bf16x8 af[4], bfr[4];
            #pragma unroll
            for (int mt = 0; mt < 4; ++mt)
                af[mt] = *(const bf16x8*)((const char*)Xs +
                         swz(mt * 16 + l15, (ko + q * 8) * 2));
            #pragma unroll
            for (int nt = 0; nt < 4; ++nt)
                bfr[nt] = *(const bf16x8*)(wr[nt] + ko + q * 8);
            #pragma unroll
            for (int mt = 0; mt < 4; ++mt)
                #pragma unroll
                for (int nt = 0; nt < 4; ++nt)
                    acc[mt][nt] = __builtin_amdgcn_mfma_f32_16x16x32_bf16(
                        af[mt], bfr[nt], acc[mt][nt], 0, 0, 0);
        }
        #pragma unroll
        for (int ks = 0; ks < 8; ++ks) {         // K 256..511: NH (LDS)
            int ko = ks * 32;
            int kw = 256 + ks * 32;
            bf16x8 af[4], bfr[4];
            #pragma unroll
            for (int mt = 0; mt < 4; ++mt) {
                int r = mt * 16 + l15;
                af[mt] = *(const bf16x8*)((const char*)Hs + swz(r, (ko + q * 8) * 2));
            }
            #pragma unroll
            for (int nt = 0; nt < 4; ++nt)
                bfr[nt] = *(const bf16x8*)(wr[nt] + kw + q * 8);
            #pragma unroll
            for (int mt = 0; mt < 4; ++mt)
                #pragma unroll
                for (int nt = 0; nt < 4; ++nt)
                    acc[mt][nt] = __builtin_amdgcn_mfma_f32_16x16x32_bf16(
                        af[mt], bfr[nt], acc[mt][nt], 0, 0, 0);
        }
        float bb[4], ww[4];
        #pragma unroll
        for (int nt = 0; nt < 4; ++nt) {
            int gc = n0w + nt * 16 + l15;
            bb[nt] = au_b1v[gc]; ww[nt] = w2v[gc];
        }
        #pragma unroll
        for (int mt = 0; mt < 4; ++mt) {
            #pragma unroll
            for (int reg = 0; reg < 4; ++reg) {
                float s = 0.f;
                #pragma unroll
                for (int nt = 0; nt < 4; ++nt)
                    s += gelu_f(acc[mt][nt][reg] + bb[nt]) * ww[nt];
                #pragma unroll
                for (int off = 1; off <= 8; off <<= 1) s += __shfl_xor(s, off);
                if (l15 == 0) rsum[wid][mt * 16 + q * 4 + reg] = s;
            }
        }
        __syncthreads();
        if (tid < 64) {
            int p = m0 + tid;
            if (p < C) {
                float z = rsum[0][tid] + rsum[1][tid] + rsum[2][tid] + rsum[3][tid] + b2s[0];
                float delta = 1.f / (1.f + expf(-z));
                float na = 0.7f * svals[b * 4096 + p] + 0.3f * delta;
                nac[(long)b * CMAX + p] = fminf(fmaxf(na, 0.f), 1.f);
            }
        }
    }
}

// ---------------- rank-256 value via binary search (shfl reduce) -------------
__global__ void __launch_bounds__(256) selectT_k(const float* __restrict__ nac,
        const int* __restrict__ cnt, float* __restrict__ T)
{
    __shared__ float v[CMAX];
    __shared__ int cs[4];
    int b = blockIdx.x, tid = threadIdx.x;
    int wid = tid >> 6, lane = tid & 63;
    int C = min(cnt[b], CMAX);
    for (int i = tid; i < CMAX; i += 256)
        v[i] = (i < C) ? nac[(long)b * CMAX + i] : -1.f;
    __syncthreads();
    float lo = 0.f, hi = 1.f;
    for (int it = 0; it < 20; ++it) {   // 1e-6 resolution << BAND_EPS
        float mid = 0.5f * (lo + hi);
        int c = 0;
        for (int i = tid; i < CMAX; i += 256) c += (v[i] >= mid) ? 1 : 0;
        #pragma unroll
        for (int off = 32; off >= 1; off >>= 1) c += __shfl_xor(c, off);
        if (lane == 0) cs[wid] = c;
        __syncthreads();
        int tot = cs[0] + cs[1] + cs[2] + cs[3];
        __syncthreads();
        if (tot >= 256) lo = mid; else hi = mid;   // uniform across threads
    }
    if (tid == 0) T[b] = lo;
}

// ---------------- compact band rows into a per-batch list ----------------
__global__ void __launch_bounds__(256) bandlist_k(const float* __restrict__ nac,
        const int* __restrict__ cnt, const float* __restrict__ Tarr,
        int* __restrict__ bandlist, int* __restrict__ bandcnt)
{
    int b = blockIdx.y;
    int C = min(cnt[b], CMAX);
    int p = blockIdx.x * 256 + threadIdx.x;
    if (p < C && fabsf(nac[(long)b * CMAX + p] - Tarr[b]) < BAND_EPS) {
        int slot = atomicAdd(&bandcnt[b], 1);
        if (slot < MAXBAND) bandlist[b * MAXBAND + slot] = p;
    }
}

// ---------------- fp32 recompute: 4 band rows per block, float4-packed W^T ---
__global__ void __launch_bounds__(256) bandfix_k(
    const float* __restrict__ hid, const int* __restrict__ sidx,
    const float* __restrict__ msgc,
    const float* __restrict__ w1Pf, const float* __restrict__ su_b1,
    const float* __restrict__ w2Pf, const float* __restrict__ su_b2,
    const float* __restrict__ ln_g, const float* __restrict__ ln_b,
    const float* __restrict__ auPf, const float* __restrict__ au_b1,
    const float* __restrict__ au_w2, const float* __restrict__ au_b2,
    const float* __restrict__ svals,
    const int* __restrict__ bandlist, const int* __restrict__ bandcnt,
    float* __restrict__ nac, unsigned short* __restrict__ NHb)
{
    int b = blockIdx.y;
    int M = min(bandcnt[b], MAXBAND);
    int base = blockIdx.x * 4;
    if (base >= M) return;
    int nact = min(M - base, 4);
    int tid = threadIdx.x;
    int wid = tid >> 6, lane = tid & 63;
    const float4* w1P = (const float4*)w1Pf;
    const float4* w2P = (const float4*)w2Pf;
    const float4* auP = (const float4*)auPf;
    __shared__ float xr[4][256];
    __shared__ float hy[4][256];
    __shared__ float nh[4][256];
    __shared__ float muS[4], rsS[4];
    __shared__ int ppS[4];
    if (tid < 4)
        ppS[tid] = (tid < nact) ? bandlist[b * MAXBAND + base + tid] : -1;
    __syncthreads();
    #pragma unroll
    for (int r = 0; r < 4; ++r) {
        int pp = ppS[r];
        xr[r][tid] = (pp >= 0) ? hid[((long)b * 4096 + sidx[b * 4096 + pp]) * 256 + tid] : 0.f;
    }
    __syncthreads();
    int n = tid;
    float acc[4];
    // ---- su1 ----
    #pragma unroll
    for (int r = 0; r < 4; ++r) acc[r] = 0.f;
    for (int k4 = 0; k4 < 64; ++k4) {
        float4 w = w1P[k4 * 256 + n];
        #pragma unroll
        for (int r = 0; r < 4; ++r) {
            float4 xv = *(const float4*)&xr[r][k4 * 4];
            acc[r] = fmaf(w.x, xv.x, acc[r]);
            acc[r] = fmaf(w.y, xv.y, acc[r]);
            acc[r] = fmaf(w.z, xv.z, acc[r]);
            acc[r] = fmaf(w.w, xv.w, acc[r]);
        }
    }
    float b1v = su_b1[n];
    #pragma unroll
    for (int r = 0; r < 4; ++r) {
        int pp = ppS[r];
        float s = acc[r] + b1v;
        if (pp >= 0 && pp < 256) s += msgc[((long)b * 256 + pp) * 256 + n];
        acc[r] = gelu_f(s);
    }
    __syncthreads();
    #pragma unroll
    for (int r = 0; r < 4; ++r) hy[r][n] = acc[r];
    __syncthreads();
    // ---- su2 ----
    #pragma unroll
    for (int r = 0; r < 4; ++r) acc[r] = 0.f;
    for (int k4 = 0; k4 < 64; ++k4) {
        float4 w = w2P[k4 * 256 + n];
        #pragma unroll
        for (int r = 0; r < 4; ++r) {
            float4 hv = *(const float4*)&hy[r][k4 * 4];
            acc[r] = fmaf(w.x, hv.x, acc[r]);
            acc[r] = fmaf(w.y, hv.y, acc[r]);
            acc[r] = fmaf(w.z, hv.z, acc[r]);
            acc[r] = fmaf(w.w, hv.w, acc[r]);
        }
    }
    __syncthreads();
    float b2v = su_b2[n];
    #pragma unroll
    for (int r = 0; r < 4; ++r) hy[r][n] = acc[r] + b2v;
    __syncthreads();
    // LN stats: wave wid handles row wid
    {
        int r = wid;
        float4 yv = *(const float4*)&hy[r][lane * 4];
        float s = yv.x + yv.y + yv.z + yv.w;
        float s2 = yv.x * yv.x + yv.y * yv.y + yv.z * yv.z + yv.w * yv.w;
        #pragma unroll
        for (int off = 32; off >= 1; off >>= 1) {
            s += __shfl_xor(s, off);
            s2 += __shfl_xor(s2, off);
        }
        if (lane == 0) {
            float mu = s * (1.f / 256.f);
            float var = s2 * (1.f / 256.f) - mu * mu;
            muS[r] = mu; rsS[r] = rsqrtf(var + 1e-5f);
        }
    }
    __syncthreads();
    float gv = ln_g[n], ev = ln_b[n];
    #pragma unroll
    for (int r = 0; r < 4; ++r) {
        float o = (hy[r][n] - muS[r]) * rsS[r] * gv + ev;
        nh[r][n] = o;
        if (ppS[r] >= 0) NHb[((long)b * CMAX + ppS[r]) * 256 + n] = f2bf(o);
    }
    __syncthreads();
    // ---- au ----
    #pragma unroll
    for (int r = 0; r < 4; ++r) acc[r] = 0.f;
    for (int k4 = 0; k4 < 64; ++k4) {
        float4 w = auP[k4 * 256 + n];
        #pragma unroll
        for (int r = 0; r < 4; ++r) {
            float4 xv = *(const float4*)&xr[r][k4 * 4];
            acc[r] = fmaf(w.x, xv.x, acc[r]);
            acc[r] = fmaf(w.y, xv.y, acc[r]);
            acc[r] = fmaf(w.z, xv.z, acc[r]);
            acc[r] = fmaf(w.w, xv.w, acc[r]);
        }
    }
    for (int k4 = 64; k4 < 128; ++k4) {
        float4 w = auP[k4 * 256 + n];
        #pragma unroll
        for (int r = 0; r < 4; ++r) {
            float4 hv = *(const float4*)&nh[r][(k4 - 64) * 4];
            acc[r] = fmaf(w.x, hv.x, acc[r]);
            acc[r] = fmaf(w.y, hv.y, acc[r]);
            acc[r] = fmaf(w.z, hv.z, acc[r]);
            acc[r] = fmaf(w.w, hv.w, acc[r]);
        }
    }
    float ab = au_b1[n], wv2 = au_w2[n];
    __syncthreads();
    #pragma unroll
    for (int r = 0; r < 4; ++r) hy[r][n] = gelu_f(acc[r] + ab) * wv2;
    __syncthreads();
    {
        int r = wid;
        float4 gvv = *(const float4*)&hy[r][lane * 4];
        float s = gvv.x + gvv.y + gvv.z + gvv.w;
        #pragma unroll
        for (int off = 32; off >= 1; off >>= 1) s += __shfl_xor(s, off);
        if (lane == 0 && ppS[r] >= 0) {
            float z = s + au_b2[0];
            float delta = 1.f / (1.f + expf(-z));
            float na = 0.7f * svals[b * 4096 + ppS[r]] + 0.3f * delta;
            nac[(long)b * CMAX + ppS[r]] = fminf(fmaxf(na, 0.f), 1.f);
        }
    }
}

// ---------------- scatter outputs ----------------
__global__ void __launch_bounds__(64) scatter_k(const float* __restrict__ selv,
        const int* __restrict__ selo, const int* __restrict__ selp,
        const unsigned short* __restrict__ NHb, float* __restrict__ out)
{
    int b = blockIdx.x >> 8, j = blockIdx.x & 255, t = threadIdx.x;
    int orig = selo[b * 256 + j];
    int p = selp[b * 256 + j];
    if (t == 0) out[b * 4096 + orig] = selv[b * 256 + j];
    const ushort4* src = (const ushort4*)(NHb + ((long)b * CMAX + p) * 256);
    ushort4 s = src[t];
    float4 o = make_float4(bf2f(s.x), bf2f(s.y), bf2f(s.z), bf2f(s.w));
    *(float4*)(out + 131072 + ((long)(b * 4096 + orig)) * 256 + t * 4) = o;
}

extern "C" void kernel_launch(void* const* d_in, const int* in_sizes, int n_in,
                              void* d_out, int out_size, void* d_ws, size_t ws_size,
                              hipStream_t stream)
{
    const float* act   = (const float*)d_in[0];
    const float* hid   = (const float*)d_in[1];
    const float* wi    = (const float*)d_in[2];
    const float* bi    = (const float*)d_in[3];
    const float* wo    = (const float*)d_in[4];
    const float* bo    = (const float*)d_in[5];
    const float* su_w1 = (const float*)d_in[6];
    const float* su_b1 = (const float*)d_in[7];
    const float* su_w2 = (const float*)d_in[8];
    const float* su_b2 = (const float*)d_in[9];
    const float* au_w1 = (const float*)d_in[10];
    const float* au_b1 = (const float*)d_in[11];
    const float* au_w2 = (const float*)d_in[12];
    const float* au_b2 = (const float*)d_in[13];
    const float* ln_g  = (const float*)d_in[14];
    const float* ln_b  = (const float*)d_in[15];
    float* out = (float*)d_out;

    char* ws = (char*)d_ws;
    size_t off = 0;
    auto alloc = [&](size_t bytes) {
        size_t o = off; off += (bytes + 255) & ~(size_t)255; return o;
    };
    float* svals = (float*)(ws + alloc((size_t)32 * 4096 * 4));
    int*   sidx  = (int*)  (ws + alloc((size_t)32 * 4096 * 4));
    int*   cnt   = (int*)  (ws + alloc(256));
    float* qkv   = (float*)(ws + alloc((size_t)32 * 256 * 768 * 4));
    float* Ob    = (float*)(ws + alloc((size_t)32 * 256 * 256 * 4));
    float* MSGC  = (float*)(ws + alloc((size_t)32 * 256 * 256 * 4));
    float* selv  = (float*)(ws + alloc((size_t)32 * 256 * 4));
    int*   selo  = (int*)  (ws + alloc((size_t)32 * 256 * 4));
    int*   selp  = (int*)  (ws + alloc((size_t)32 * 256 * 4));
    unsigned short* swb1 = (unsigned short*)(ws + alloc((size_t)256 * 512 * 2));
    unsigned short* swb2 = (unsigned short*)(ws + alloc((size_t)256 * 256 * 2));
    unsigned short* awb1 = (unsigned short*)(ws + alloc((size_t)256 * 512 * 2));
    float* w1P = (float*)(ws + alloc((size_t)256 * 256 * 4));
    float* w2P = (float*)(ws + alloc((size_t)256 * 256 * 4));
    float* auP = (float*)(ws + alloc((size_t)512 * 256 * 4));
    unsigned short* Xb   = (unsigned short*)(ws + alloc((size_t)32 * CMAX * 256 * 2));
    unsigned short* NHb  = (unsigned short*)(ws + alloc((size_t)32 * CMAX * 256 * 2));
    float* nac = (float*)(ws + alloc((size_t)32 * CMAX * 4));
    float* Tb  = (float*)(ws + alloc(128));
    int* bandl = (int*)(ws + alloc((size_t)32 * MAXBAND * 4));
    int* bandc = (int*)(ws + alloc(128));

    // 0. zero band counters
    hipMemsetAsync(bandc, 0, 32 * sizeof(int), stream);
    // 1. zero outputs
    fill0_k<<<2048, 256, 0, stream>>>((float4*)out, (long)out_size / 4);
    // 2. radix-select activations (deterministic index-order compaction)
    topk1_k<<<32, 256, 0, stream>>>(act, svals, sidx, cnt);
    // 3. weight conversion + packed fp32 transposes (single launch)
    prep_k<<<768, 256, 0, stream>>>(su_w1, su_w2, au_w1, swb1, swb2, awb1,
                                    w1P, w2P, auP);
    // 4. gather + bf16 candidate rows
    gatherX_k<<<dim3(CMAX / 4, 32), 256, 0, stream>>>(hid, sidx, cnt, Xb);
    // 5. qkv = gather(hidden) @ wi^T + bi
    gemm_k<64, 256, 8, 8, true, true, 1><<<dim3(3, 4, 32), 256, 0, stream>>>(
        hid, 256, (long)4096 * 256, 0, 1,
        wi, 256, 0, 0, 1,
        qkv, 768, (long)256 * 768, 0, 1,
        256, bi, nullptr, 0, sidx, 4096, 0.f);
    // 6. O = softmax(QK^T/8) @ V  -- S lives in LDS
    attn_k<<<dim3(8, 4, 32), 256, 0, stream>>>(qkv, Ob);
    // 7. MSGC = ((O @ wo^T + bo) * tv) @ W1b^T
    msgc_k<<<dim3(8, 32), 256, 0, stream>>>(Ob, wo, bo, su_w1, svals, MSGC);
    // 8. fused candidate-row MLP (su1 -> su2+LN -> au), bf16 MFMA + LDS
    fused_mlp_k<<<dim3(CMAX / 64, 32), 256, 0, stream>>>(Xb, swb1, swb2, awb1,
        su_b1, MSGC, su_b2, ln_g, ln_b, au_b1, au_w2, au_b2, svals, cnt,
        NHb, nac);
    // 9. rank-256 value per batch (band center)
    selectT_k<<<32, 256, 0, stream>>>(nac, cnt, Tb);
    // 10a. compact band rows
    bandlist_k<<<dim3(CMAX / 256, 32), 256, 0, stream>>>(nac, cnt, Tb, bandl, bandc);
    // 10b. fp32 recompute of boundary-band rows, 4 rows/block, packed W^T
    bandfix_k<<<dim3(MAXBAND / 4, 32), 256, 0, stream>>>(hid, sidx, MSGC,
        w1P, su_b1, w2P, su_b2, ln_g, ln_b, auP, au_b1, au_w2, au_b2,
        svals, bandl, bandc, nac, NHb);
    // 11. exact top-256 selection over corrected new activations
    topk2_k<<<32, 256, 0, stream>>>(nac, sidx, cnt, selv, selo, selp);
    // 12. scatter selected rows
    scatter_k<<<8192, 64, 0, stream>>>(selv, selo, selp, NHb, out);
}

// Round 10
// 684.464 us; speedup vs baseline: 1.0490x; 1.0490x over previous
//
#include <hip/hip_runtime.h>

// NeuronInteraction: B=32, N=4096, D=256, H=4, hd=64, MSG_K=256, k=256
// Pipeline:
//  fill0 -> topk1(radix-select, DETERMINISTIC index-order compaction) ->
//  prep(bf16 weights + packed W^T) -> gatherX -> qkv GEMM -> S+softmax GEMM
//  (EPI=4) -> PV GEMM -> msgc_k -> FUSED bf16 MFMA MLP -> selectT ->
//  bandlist -> bandfix -> topk2 -> scatter.
// R9 post-mortem: attn_k (S-in-LDS fusion) measured a +28us REGRESSION vs the
// two-GEMM path (75KB LDS -> 2 blocks/CU, serialized phases; the Sb round-trip
// it eliminated was L3-absorbed anyway). Reverted permanently. Deterministic
// topk1 kept (replay-flip insurance, ~2us). R10: attention-chain GEMM grids
// were half-idle (384/512 blocks, 256 CUs x 3 blocks/CU): step5 retiled
// 64x256->64x128 (768 blocks), step6 64x256->32x256 (1024 blocks). Tile shape
// does not change per-element fp32 k-accumulation order -> bit-identical.
// BAND_EPS=0.004: bf16-path na error max-stat ~1.1e-4 (36x margin).

constexpr int KC = 32;
constexpr int CMAX = 2304;           // E[cands]=2012, sigma~32 -> +9 sigma
constexpr float BAND_EPS = 0.004f;
constexpr int MAXBAND = 512;         // E[band]~47 -> 10x margin

typedef short bf16x8 __attribute__((ext_vector_type(8)));
typedef float f32x4 __attribute__((ext_vector_type(4)));

__device__ __forceinline__ float gelu_f(float x) {
    return 0.5f * x * (1.0f + erff(x * 0.70710678118654752440f));
}
__device__ __forceinline__ unsigned short f2bf(float f) {
    unsigned u = __float_as_uint(f);
    return (unsigned short)((u + 0x7fffu + ((u >> 16) & 1u)) >> 16);
}
__device__ __forceinline__ float bf2f(unsigned short h) {
    return __uint_as_float(((unsigned)h) << 16);
}
// XOR swizzle for a [R][256] bf16 LDS tile (row stride 512B): spreads the
// 16B granules of 8 consecutive rows across distinct banks so that
// ds_read_b128 of {rows r..r+15, same col-chunk} is ~2-way (free, m136).
__device__ __forceinline__ int swz(int row, int byteInRow) {
    return (row << 9) + (byteInRow ^ ((row & 7) << 4));
}

// ---------------- zero-fill output ----------------
__global__ void __launch_bounds__(256) fill0_k(float4* p, long n4) {
    long i = (long)blockIdx.x * 256 + threadIdx.x;
    long stride = (long)gridDim.x * 256;
    float4 z = make_float4(0.f, 0.f, 0.f, 0.f);
    for (; i < n4; i += stride) p[i] = z;
}

// ---------------- top-k #1: radix threshold + DETERMINISTIC compaction ------
// Slots assigned in ascending element-index order via prefix-sum compaction
// (no atomics) so the candidate permutation is a pure function of the data.
__global__ void __launch_bounds__(256) topk1_k(const float* __restrict__ act,
        float* __restrict__ svals, int* __restrict__ sidx, int* __restrict__ cnt)
{
    __shared__ int cs[4];
    int b = blockIdx.x, tid = threadIdx.x;
    int wid = tid >> 6, lane = tid & 63;
    unsigned v[16];
    #pragma unroll
    for (int s = 0; s < 16; ++s)
        v[s] = __float_as_uint(act[b * 4096 + s * 256 + tid]); // >=0: bits monotone

    auto reduce4 = [&](int c) -> int {
        #pragma unroll
        for (int off = 32; off >= 1; off >>= 1) c += __shfl_xor(c, off);
        if (lane == 0) cs[wid] = c;
        __syncthreads();
        int tot = cs[0] + cs[1] + cs[2] + cs[3];
        __syncthreads();
        return tot;
    };
    auto countGE = [&](unsigned thr) -> int {
        int c = 0;
        #pragma unroll
        for (int s = 0; s < 16; ++s) c += (v[s] >= thr) ? 1 : 0;
        return reduce4(c);
    };
    auto countEqLt = [&](unsigned vs, int icut) -> int {
        int c = 0;
        #pragma unroll
        for (int s = 0; s < 16; ++s)
            c += (v[s] == vs && (s * 256 + tid) < icut) ? 1 : 0;
        return reduce4(c);
    };

    unsigned vstar = 0;
    for (int bit = 31; bit >= 0; --bit) {
        unsigned cand = vstar | (1u << bit);
        if (countGE(cand) >= 256) vstar = cand;
    }
    int cgt = countGE(vstar + 1);
    int needed = 256 - cgt;
    int icut = 4096;
    if (countEqLt(vstar, 4096) > needed) {
        int lo = 0, hi = 4096;
        for (int it = 0; it < 12; ++it) {
            int mid = (lo + hi) >> 1;
            if (countEqLt(vstar, mid) <= needed) lo = mid; else hi = mid;
        }
        icut = lo;
    }
    // ---- deterministic compaction: packed {top, rest} prefix sums ----
    // (entering here barrier-synced: reduce4 ends with __syncthreads)
    float th = __uint_as_float(vstar) - 0.4288f;  // > 3/7 margin
    int basePacked = 0;   // low 16: top base, high 16: rest base (uniform)
    for (int s = 0; s < 16; ++s) {
        int i = s * 256 + tid;
        unsigned vb = v[s];
        float f = __uint_as_float(vb);
        bool top = (vb > vstar) || (vb == vstar && i < icut);
        bool rest = (!top) && (f >= th);
        int flag = (top ? 1 : 0) | (rest ? (1 << 16) : 0);
        int x = flag;
        #pragma unroll
        for (int off = 1; off < 64; off <<= 1) {   // inclusive scan in wave
            int n = __shfl_up(x, off);
            if (lane >= off) x += n;
        }
        if (lane == 63) cs[wid] = x;
        __syncthreads();
        int waveOff = 0;
        #pragma unroll
        for (int w = 0; w < 4; ++w) if (w < wid) waveOff += cs[w];
        int tot = cs[0] + cs[1] + cs[2] + cs[3];
        int excl = x - flag + waveOff;             // exclusive prefix (packed)
        if (top) {
            int slot = (basePacked & 0xffff) + (excl & 0xffff);
            sidx[b * 4096 + slot] = i;
            svals[b * 4096 + slot] = f;
        } else if (rest) {
            int slot = 256 + (basePacked >> 16) + (excl >> 16);
            if (slot < CMAX) {
                sidx[b * 4096 + slot] = i;
                svals[b * 4096 + slot] = f;
            }
        }
        basePacked += tot;
        __syncthreads();   // protect cs reuse next round
    }
    if (tid == 0) cnt[b] = min(256 + (basePacked >> 16), CMAX);
}

// ---------------- top-k #2: radix threshold selection over candidates --------
// (atomic slot order is fine here: each output entry depends only on itself)
__global__ void __launch_bounds__(256) topk2_k(const float* __restrict__ newact,
        const int* __restrict__ sidx, const int* __restrict__ cnt,
        float* __restrict__ selv, int* __restrict__ selo, int* __restrict__ selp)
{
    __shared__ int cs[4];
    __shared__ int sSel;
    int b = blockIdx.x, tid = threadIdx.x;
    int wid = tid >> 6, lane = tid & 63;
    int C = min(cnt[b], CMAX);
    unsigned v[9];
    int org[9];
    #pragma unroll
    for (int s = 0; s < 9; ++s) {
        int p = s * 256 + tid;
        bool ok = (p < C && p < CMAX);
        v[s] = ok ? __float_as_uint(newact[(long)b * CMAX + p]) : 0u;
        org[s] = ok ? sidx[b * 4096 + p] : 0x7FFFFFFF;
    }
    auto reduce4 = [&](int c) -> int {
        #pragma unroll
        for (int off = 32; off >= 1; off >>= 1) c += __shfl_xor(c, off);
        if (lane == 0) cs[wid] = c;
        __syncthreads();
        int tot = cs[0] + cs[1] + cs[2] + cs[3];
        __syncthreads();
        return tot;
    };
    auto countGE = [&](unsigned thr) -> int {
        int c = 0;
        #pragma unroll
        for (int s = 0; s < 9; ++s) c += (v[s] >= thr) ? 1 : 0;
        return reduce4(c);
    };
    auto countEqLt = [&](unsigned vs, int icut) -> int {
        int c = 0;
        #pragma unroll
        for (int s = 0; s < 9; ++s) c += (v[s] == vs && org[s] < icut) ? 1 : 0;
        return reduce4(c);
    };

    unsigned vstar = 0;
    for (int bit = 31; bit >= 0; --bit) {
        unsigned cand = vstar | (1u << bit);
        if (countGE(cand) >= 256) vstar = cand;
    }
    int cgt = countGE(vstar + 1);
    int needed = 256 - cgt;
    int icut = 4096;
    if (countEqLt(vstar, 4096) > needed) {
        int lo = 0, hi = 4096;
        for (int it = 0; it < 12; ++it) {
            int mid = (lo + hi) >> 1;
            if (countEqLt(vstar, mid) <= needed) lo = mid; else hi = mid;
        }
        icut = lo;
    }
    if (tid == 0) sSel = 0;
    __syncthreads();
    #pragma unroll
    for (int s = 0; s < 9; ++s) {
        unsigned vb = v[s];
        bool sel = (vb > vstar) || (vb == vstar && org[s] < icut);
        if (sel) {
            int slot = atomicAdd(&sSel, 1);
            selv[b * 256 + slot] = __uint_as_float(vb);
            selo[b * 256 + slot] = org[s];
            selp[b * 256 + slot] = s * 256 + tid;
        }
    }
}

// ---------------- generic fp32 tiled GEMM (attention chain) ----------------
// EPI: 0 none, 1 +bias, 2 +bias*rowscale, 3 *cscale, 4 row-softmax(cscale)
template<int TM, int TN, int RM, int RN, bool BT, bool GATHER, int EPI>
__global__ void __launch_bounds__(256) gemm_k(
    const float* __restrict__ A, int lda, long sA1, long sA2, int divA,
    const float* __restrict__ B, int ldb, long sB1, long sB2, int divB,
    float* __restrict__ C, int ldc, long sC1, long sC2, int divC,
    int K, const float* __restrict__ bias, const float* __restrict__ rowscale,
    long rsStride, const int* __restrict__ gmap, long gmapStride, float cscale)
{
    constexpr int TX = TN / RN, TY = TM / RM;
    static_assert(TX * TY == 256, "block must be 256 threads");
    static_assert(EPI != 4 || TX == 32, "softmax epilogue needs TX==32");
    static_assert(RM >= 4 && RN >= 4, "float4 register reads need RM,RN >= 4");
    __shared__ float As[KC][TM + 4];
    __shared__ float Bs[KC][TN + 4];
    int z = blockIdx.z;
    const float* Ab = A + (long)(z / divA) * sA1 + (long)(z % divA) * sA2;
    const float* Bb = B + (long)(z / divB) * sB1 + (long)(z % divB) * sB2;
    float* Cb = C + (long)(z / divC) * sC1 + (long)(z % divC) * sC2;
    int m0 = blockIdx.y * TM, n0 = blockIdx.x * TN;
    int tid = threadIdx.x;
    int tx = tid % TX, ty = tid / TX;
    float acc[RM][RN];
    #pragma unroll
    for (int i = 0; i < RM; ++i)
        #pragma unroll
        for (int j = 0; j < RN; ++j) acc[i][j] = 0.f;

    for (int k0 = 0; k0 < K; k0 += KC) {
        __syncthreads();
        #pragma unroll
        for (int u = 0; u < (TM * KC) / 1024; ++u) {
            int idx = tid + u * 256;
            int m = idx / (KC / 4), k4 = idx % (KC / 4);
            int row = m0 + m;
            long grow = GATHER ? (long)gmap[(long)z * gmapStride + row] : (long)row;
            float4 v = *(const float4*)(Ab + grow * lda + k0 + k4 * 4);
            As[k4 * 4 + 0][m] = v.x; As[k4 * 4 + 1][m] = v.y;
            As[k4 * 4 + 2][m] = v.z; As[k4 * 4 + 3][m] = v.w;
        }
        if (BT) {
            #pragma unroll
            for (int u = 0; u < (TN * KC) / 1024; ++u) {
                int idx = tid + u * 256;
                int n = idx / (KC / 4), k4 = idx % (KC / 4);
                float4 v = *(const float4*)(Bb + (long)(n0 + n) * ldb + k0 + k4 * 4);
                Bs[k4 * 4 + 0][n] = v.x; Bs[k4 * 4 + 1][n] = v.y;
                Bs[k4 * 4 + 2][n] = v.z; Bs[k4 * 4 + 3][n] = v.w;
            }
        } else {
            #pragma unroll
            for (int u = 0; u < (TN * KC) / 1024; ++u) {
                int idx = tid + u * 256;
                int k = idx / (TN / 4), n4 = idx % (TN / 4);
                float4 v = *(const float4*)(Bb + (long)(k0 + k) * ldb + n0 + n4 * 4);
                *(float4*)&Bs[k][n4 * 4] = v;
            }
        }
        __syncthreads();
        #pragma unroll
        for (int k = 0; k < KC; ++k) {
            float av[RM], bv[RN];
            #pragma unroll
            for (int i = 0; i < RM; i += 4) {
                float4 t = *(const float4*)&As[k][ty * RM + i];
                av[i] = t.x; av[i + 1] = t.y; av[i + 2] = t.z; av[i + 3] = t.w;
            }
            #pragma unroll
            for (int j = 0; j < RN; j += 4) {
                float4 t = *(const float4*)&Bs[k][tx * RN + j];
                bv[j] = t.x; bv[j + 1] = t.y; bv[j + 2] = t.z; bv[j + 3] = t.w;
            }
            #pragma unroll
            for (int i = 0; i < RM; ++i)
                #pragma unroll
                for (int j = 0; j < RN; ++j)
                    acc[i][j] = fmaf(av[i], bv[j], acc[i][j]);
        }
    }
    if (EPI == 4) {
        // fused row softmax: block owns the FULL row (n0==0, TN==K-range).
        // Row r is held by the 32 same-ty threads; they sit in one 32-lane
        // half-wave (tid = ty*32+tx) so shfl_xor(<=16) reduces exactly over r.
        #pragma unroll
        for (int i = 0; i < RM; ++i) {
            float m = -1e30f;
            #pragma unroll
            for (int j = 0; j < RN; ++j) {
                acc[i][j] *= cscale;
                m = fmaxf(m, acc[i][j]);
            }
            #pragma unroll
            for (int off = 16; off >= 1; off >>= 1) m = fmaxf(m, __shfl_xor(m, off));
            float s = 0.f;
            #pragma unroll
            for (int j = 0; j < RN; ++j) {
                acc[i][j] = expf(acc[i][j] - m);
                s += acc[i][j];
            }
            #pragma unroll
            for (int off = 16; off >= 1; off >>= 1) s += __shfl_xor(s, off);
            float inv = 1.f / s;
            #pragma unroll
            for (int j = 0; j < RN; ++j) acc[i][j] *= inv;
        }
    }
    #pragma unroll
    for (int i = 0; i < RM; ++i) {
        int gm = m0 + ty * RM + i;
        float rs = 1.f;
        if (EPI == 2) rs = rowscale[(long)z * rsStride + gm];
        #pragma unroll
        for (int j = 0; j < RN; j += 4) {
            int gn = n0 + tx * RN + j;
            float4 v = make_float4(acc[i][j], acc[i][j + 1], acc[i][j + 2], acc[i][j + 3]);
            if (EPI == 1 || EPI == 2) {
                float4 bb = *(const float4*)(bias + gn);
                v.x += bb.x; v.y += bb.y; v.z += bb.z; v.w += bb.w;
            }
            if (EPI == 2) { v.x *= rs; v.y *= rs; v.z *= rs; v.w *= rs; }
            if (EPI == 3) { v.x *= cscale; v.y *= cscale; v.z *= cscale; v.w *= cscale; }
            *(float4*)(Cb + (long)gm * ldc + gn) = v;
        }
    }
}

// ---------------- fused: MSGC = ((O@wo^T+bo)*tv) @ W1b^T ---------
// Block = 32 MSG rows x 256 cols; MSG tile lives in LDS (never hits global).
__global__ void __launch_bounds__(256) msgc_k(
    const float* __restrict__ Ob,     // [32][256][256]
    const float* __restrict__ wo,     // [256][256]
    const float* __restrict__ bo,     // [256]
    const float* __restrict__ su_w1,  // [256][512]; cols 256.. = W1b
    const float* __restrict__ svals,  // tv = svals[b*4096 + row]
    float* __restrict__ MSGC)         // [32][256][256]
{
    constexpr int TM = 32, TN = 256, RM = 4, RN = 8;
    constexpr int TX = TN / RN;  // 32
    __shared__ float As[KC][TM + 4];
    __shared__ float Bs[KC][TN + 4];
    __shared__ float Ms[TM][TN + 4];  // MSG tile [m][k]
    int b = blockIdx.y;
    int m0 = blockIdx.x * TM;
    int tid = threadIdx.x;
    int tx = tid % TX, ty = tid / TX;
    const float* Ab = Ob + (long)b * 65536;
    float acc[RM][RN];

    // ---- phase 1: MSG = O @ wo^T + bo, scaled by tv ----
    #pragma unroll
    for (int i = 0; i < RM; ++i)
        #pragma unroll
        for (int j = 0; j < RN; ++j) acc[i][j] = 0.f;
    for (int k0 = 0; k0 < 256; k0 += KC) {
        __syncthreads();
        {   // stage A: 32 rows x KC  (1 float4/thread)
            int m = tid / (KC / 4), k4 = tid % (KC / 4);
            float4 v = *(const float4*)(Ab + (long)(m0 + m) * 256 + k0 + k4 * 4);
            As[k4 * 4 + 0][m] = v.x; As[k4 * 4 + 1][m] = v.y;
            As[k4 * 4 + 2][m] = v.z; As[k4 * 4 + 3][m] = v.w;
        }
        #pragma unroll
        for (int u = 0; u < 8; ++u) {  // stage B (wo, BT): 256 n x KC
            int idx = tid + u * 256;
            int n = idx / (KC / 4), k4 = idx % (KC / 4);
            float4 v = *(const float4*)(wo + (long)n * 256 + k0 + k4 * 4);
            Bs[k4 * 4 + 0][n] = v.x; Bs[k4 * 4 + 1][n] = v.y;
            Bs[k4 * 4 + 2][n] = v.z; Bs[k4 * 4 + 3][n] = v.w;
        }
        __syncthreads();
        #pragma unroll
        for (int k = 0; k < KC; ++k) {
            float av[RM], bv[RN];
            float4 ta = *(const float4*)&As[k][ty * RM];
            av[0] = ta.x; av[1] = ta.y; av[2] = ta.z; av[3] = ta.w;
            #pragma unroll
            for (int j = 0; j < RN; j += 4) {
                float4 t = *(const float4*)&Bs[k][tx * RN + j];
                bv[j] = t.x; bv[j + 1] = t.y; bv[j + 2] = t.z; bv[j + 3] = t.w;
            }
            #pragma unroll
            for (int i = 0; i < RM; ++i)
                #pragma unroll
                for (int j = 0; j < RN; ++j)
                    acc[i][j] = fmaf(av[i], bv[j], acc[i][j]);
        }
    }
    __syncthreads();   // As/Bs reuse below; also orders Ms writes
    #pragma unroll
    for (int i = 0; i < RM; ++i) {
        int gm = m0 + ty * RM + i;
        float tv = svals[b * 4096 + gm];
        #pragma unroll
        for (int j = 0; j < RN; j += 4) {
            int gn = tx * RN + j;
            float4 bb = *(const float4*)(bo + gn);
            float4 v;
            v.x = (acc[i][j + 0] + bb.x) * tv;
            v.y = (acc[i][j + 1] + bb.y) * tv;
            v.z = (acc[i][j + 2] + bb.z) * tv;
            v.w = (acc[i][j + 3] + bb.w) * tv;
            *(float4*)&Ms[ty * RM + i][gn] = v;
        }
    }

    // ---- phase 2: MSGC = MSG @ W1b^T ----
    #pragma unroll
    for (int i = 0; i < RM; ++i)
        #pragma unroll
        for (int j = 0; j < RN; ++j) acc[i][j] = 0.f;
    const float* W1b = su_w1 + 256;
    for (int k0 = 0; k0 < 256; k0 += KC) {
        __syncthreads();
        #pragma unroll
        for (int u = 0; u < 8; ++u) {  // stage B (W1b, BT, ldb=512)
            int idx = tid + u * 256;
            int n = idx / (KC / 4), k4 = idx % (KC / 4);
            float4 v = *(const float4*)(W1b + (long)n * 512 + k0 + k4 * 4);
            Bs[k4 * 4 + 0][n] = v.x; Bs[k4 * 4 + 1][n] = v.y;
            Bs[k4 * 4 + 2][n] = v.z; Bs[k4 * 4 + 3][n] = v.w;
        }
        __syncthreads();
        #pragma unroll
        for (int k = 0; k < KC; ++k) {
            float av[RM], bv[RN];
            #pragma unroll
            for (int i = 0; i < RM; ++i)
                av[i] = Ms[ty * RM + i][k0 + k];   // broadcast reads
            #pragma unroll
            for (int j = 0; j < RN; j += 4) {
                float4 t = *(const float4*)&Bs[k][tx * RN + j];
                bv[j] = t.x; bv[j + 1] = t.y; bv[j + 2] = t.z; bv[j + 3] = t.w;
            }
            #pragma unroll
            for (int i = 0; i < RM; ++i)
                #pragma unroll
                for (int j = 0; j < RN; ++j)
                    acc[i][j] = fmaf(av[i], bv[j], acc[i][j]);
        }
    }
    float* Cb = MSGC + (long)b * 65536;
    #pragma unroll
    for (int i = 0; i < RM; ++i) {
        int gm = m0 + ty * RM + i;
        #pragma unroll
        for (int j = 0; j < RN; j += 4) {
            int gn = tx * RN + j;
            float4 v = make_float4(acc[i][j], acc[i][j + 1], acc[i][j + 2], acc[i][j + 3]);
            *(float4*)(Cb + (long)gm * 256 + gn) = v;
        }
    }
}

// ---------------- prep: bf16 weight conversion + packed fp32 transposes ------
// blocks 0..511: bf16 convert. 512..575: w1P, 576..639: w2P, 640..767: auP.
// Packed layout: dst float4 index (k>>2)*256 + n holds w[k..k+3][n].
__global__ void __launch_bounds__(256) prep_k(
        const float* __restrict__ s1, const float* __restrict__ s2,
        const float* __restrict__ a1,
        unsigned short* __restrict__ o1, unsigned short* __restrict__ o2,
        unsigned short* __restrict__ o3,
        float* __restrict__ w1P, float* __restrict__ w2P, float* __restrict__ auP)
{
    int blk = blockIdx.x, tid = threadIdx.x;
    if (blk < 512) {
        int i = blk * 256 + tid;
        o1[i] = f2bf(s1[i]);
        o3[i] = f2bf(a1[i]);
        if (i < 65536) o2[i] = f2bf(s2[i]);
        return;
    }
    const float* src; float* dst; int ld, ktiles, rel;
    if (blk < 576) { rel = blk - 512; src = s1; ld = 512; dst = w1P; ktiles = 8; }
    else if (blk < 640) { rel = blk - 576; src = s2; ld = 256; dst = w2P; ktiles = 8; }
    else { rel = blk - 640; src = a1; ld = 512; dst = auP; ktiles = 16; }
    int k0 = (rel % ktiles) * 32, n0 = (rel / ktiles) * 32;
    __shared__ float t[32][33];
    int tx = tid & 31, ty = tid >> 5;
    #pragma unroll
    for (int yy = 0; yy < 4; ++yy) {
        int nl = ty * 4 + yy;
        t[nl][tx] = src[(long)(n0 + nl) * ld + k0 + tx];
    }
    __syncthreads();
    #pragma unroll
    for (int yy = 0; yy < 4; ++yy) {
        int k = k0 + ty * 4 + yy;
        dst[(long)(k >> 2) * 1024 + (n0 + tx) * 4 + (k & 3)] = t[tx][ty * 4 + yy];
    }
}

// ---------------- gather candidate rows -> bf16 [B][CMAX][256] ----------------
__global__ void __launch_bounds__(256) gatherX_k(const float* __restrict__ hid,
        const int* __restrict__ sidx, const int* __restrict__ cnt,
        unsigned short* __restrict__ Xb)
{
    int b = blockIdx.y;
    int C = min(cnt[b], CMAX);
    int p = blockIdx.x * 4 + (threadIdx.x >> 6);
    int lane = threadIdx.x & 63;
    unsigned short* dst = Xb + ((long)b * CMAX + p) * 256 + lane * 4;
    if (p < C) {
        int row = sidx[b * 4096 + p];
        float4 v = *(const float4*)(hid + ((long)b * 4096 + row) * 256 + lane * 4);
        ushort4 o; o.x = f2bf(v.x); o.y = f2bf(v.y); o.z = f2bf(v.z); o.w = f2bf(v.w);
        *(ushort4*)dst = o;
    } else {
        ushort4 z; z.x = 0; z.y = 0; z.z = 0; z.w = 0;
        *(ushort4*)dst = z;
    }
}

// ---------------- FUSED bf16 MFMA MLP: su1 -> su2+LN -> au in one kernel -----
// (R4 variant, measured ~153us.) Block = 64 rows x 256 cols, 4 waves.
// X staged once into swizzled LDS (reused stages A+C); H1/NH in 2nd tile.
__global__ void __launch_bounds__(256, 2) fused_mlp_k(
    const unsigned short* __restrict__ Xb,
    const unsigned short* __restrict__ W1,   // [256][512] bf16, K used: 0..255
    const unsigned short* __restrict__ W2,   // [256][256] bf16
    const unsigned short* __restrict__ WA,   // [256][512] bf16, full K
    const float* __restrict__ su_b1v, const float* __restrict__ msgc,
    const float* __restrict__ su_b2v,
    const float* __restrict__ lng, const float* __restrict__ lnb,
    const float* __restrict__ au_b1v,
    const float* __restrict__ w2v, const float* __restrict__ b2s,
    const float* __restrict__ svals, const int* __restrict__ cnt,
    unsigned short* __restrict__ NHb, float* __restrict__ nac)
{
    int b = blockIdx.y;
    int C = min(cnt[b], CMAX);
    int m0 = blockIdx.x * 64;
    if (m0 >= C) return;
    int tid = threadIdx.x;
    int wid = tid >> 6;
    int lane = tid & 63;
    int l15 = lane & 15;
    int q = lane >> 4;
    int n0w = wid * 64;

    __shared__ __align__(16) unsigned short Xs[64 * 256]; // swizzled X tile
    __shared__ __align__(16) unsigned short Hs[64 * 256]; // swizzled H1/NH tile
    __shared__ float rsum[4][64];
    __shared__ float rsq[4][64];
    __shared__ float rmu[64], rrs[64];

    const unsigned short* Ab = Xb + ((long)b * CMAX + m0) * 256;

    #pragma unroll
    for (int rnd = 0; rnd < 8; ++rnd) {
        int idx = rnd * 256 + tid;
        int r = idx >> 5, c = idx & 31;
        bf16x8 v = *(const bf16x8*)(Ab + r * 256 + c * 8);
        *(bf16x8*)((char*)Xs + swz(r, c * 16)) = v;
    }
    __syncthreads();

    f32x4 acc[4][4];

    // ================= stage A: H1 = gelu(X @ W1[:, :256]^T + b1 + msgc) ====
    #pragma unroll
    for (int mt = 0; mt < 4; ++mt)
        #pragma unroll
        for (int nt = 0; nt < 4; ++nt) {
            f32x4 z = {0.f, 0.f, 0.f, 0.f};
            acc[mt][nt] = z;
        }
    {
        const unsigned short* wr[4];
        #pragma unroll
        for (int nt = 0; nt < 4; ++nt) wr[nt] = W1 + (long)(n0w + nt * 16 + l15) * 512;
        #pragma unroll 4
        for (int ks = 0; ks < 8; ++ks) {
            int ko = ks * 32;
            bf16x8 af[4], bfr[4];
            #pragma unroll
            for (int mt = 0; mt < 4; ++mt)
                af[mt] = *(const bf16x8*)((const char*)Xs +
                         swz(mt * 16 + l15, (ko + q * 8) * 2));
            #pragma unroll
            for (int nt = 0; nt < 4; ++nt)
                bfr[nt] = *(const bf16x8*)(wr[nt] + ko + q * 8);
            #pragma unroll
            for (int mt = 0; mt < 4; ++mt)
                #pragma unroll
                for (int nt = 0; nt < 4; ++nt)
                    acc[mt][nt] = __builtin_amdgcn_mfma_f32_16x16x32_bf16(
                        af[mt], bfr[nt], acc[mt][nt], 0, 0, 0);
        }
        float bb[4];
        #pragma unroll
        for (int nt = 0; nt < 4; ++nt) bb[nt] = su_b1v[n0w + nt * 16 + l15];
        #pragma unroll
        for (int mt = 0; mt < 4; ++mt) {
            #pragma unroll
            for (int reg = 0; reg < 4; ++reg) {
                int lr = mt * 16 + q * 4 + reg;
                int p = m0 + lr;
                const float* mrow = msgc + ((long)b * 256 + p) * 256;
                bool hasm = (p < 256);
                #pragma unroll
                for (int nt = 0; nt < 4; ++nt) {
                    int gc = n0w + nt * 16 + l15;
                    float v = acc[mt][nt][reg] + bb[nt];
                    if (hasm) v += mrow[gc];
                    *(unsigned short*)((char*)Hs + swz(lr, gc * 2)) = f2bf(gelu_f(v));
                }
            }
        }
    }
    __syncthreads();

    // ================= stage B: NH = LN(H1 @ W2^T + b2) =====================
    #pragma unroll
    for (int mt = 0; mt < 4; ++mt)
        #pragma unroll
        for (int nt = 0; nt < 4; ++nt) {
            f32x4 z = {0.f, 0.f, 0.f, 0.f};
            acc[mt][nt] = z;
        }
    {
        const unsigned short* wr[4];
        #pragma unroll
        for (int nt = 0; nt < 4; ++nt) wr[nt] = W2 + (long)(n0w + nt * 16 + l15) * 256;
        #pragma unroll
        for (int ks = 0; ks < 8; ++ks) {
            int ko = ks * 32;
            bf16x8 af[4], bfr[4];
            #pragma unroll
            for (int mt = 0; mt < 4; ++mt) {
                int r = mt * 16 + l15;
                af[mt] = *(const bf16x8*)((const char*)Hs + swz(r, (ko + q * 8) * 2));
            }
            #pragma unroll
            for (int nt = 0; nt < 4; ++nt)
                bfr[nt] = *(const bf16x8*)(wr[nt] + ko + q * 8);
            #pragma unroll
            for (int mt = 0; mt < 4; ++mt)
                #pragma unroll
                for (int nt = 0; nt < 4; ++nt)
                    acc[mt][nt] = __builtin_amdgcn_mfma_f32_16x16x32_bf16(
                        af[mt], bfr[nt], acc[mt][nt], 0, 0, 0);
        }
        float bb[4], gg[4], eb[4];
        #pragma unroll
        for (int nt = 0; nt < 4; ++nt) {
            int gc = n0w + nt * 16 + l15;
            bb[nt] = su_b2v[gc]; gg[nt] = lng[gc]; eb[nt] = lnb[gc];
        }
        #pragma unroll
        for (int mt = 0; mt < 4; ++mt)
            #pragma unroll
            for (int nt = 0; nt < 4; ++nt)
                #pragma unroll
                for (int reg = 0; reg < 4; ++reg)
                    acc[mt][nt][reg] += bb[nt];
        #pragma unroll
        for (int mt = 0; mt < 4; ++mt) {
            #pragma unroll
            for (int reg = 0; reg < 4; ++reg) {
                float s = 0.f, s2 = 0.f;
                #pragma unroll
                for (int nt = 0; nt < 4; ++nt) {
                    float v = acc[mt][nt][reg];
                    s += v; s2 += v * v;
                }
                #pragma unroll
                for (int off = 1; off <= 8; off <<= 1) {
                    s += __shfl_xor(s, off);
                    s2 += __shfl_xor(s2, off);
                }
                if (l15 == 0) {
                    int row = mt * 16 + q * 4 + reg;
                    rsum[wid][row] = s; rsq[wid][row] = s2;
                }
            }
        }
        __syncthreads();   // all waves past MFMA loop -> Hs reads complete
        if (tid < 64) {
            float s = rsum[0][tid] + rsum[1][tid] + rsum[2][tid] + rsum[3][tid];
            float s2 = rsq[0][tid] + rsq[1][tid] + rsq[2][tid] + rsq[3][tid];
            float mu = s * (1.f / 256.f);
            float var = s2 * (1.f / 256.f) - mu * mu;
            rmu[tid] = mu;
            rrs[tid] = rsqrtf(var + 1e-5f);
        }
        __syncthreads();
        #pragma unroll
        for (int mt = 0; mt < 4; ++mt) {
            #pragma unroll
            for (int reg = 0; reg < 4; ++reg) {
                int lr = mt * 16 + q * 4 + reg;
                float mu = rmu[lr], rs = rrs[lr];
                #pragma unroll
                for (int nt = 0; nt < 4; ++nt) {
                    int gc = n0w + nt * 16 + l15;
                    unsigned short ov =
                        f2bf((acc[mt][nt][reg] - mu) * rs * gg[nt] + eb[nt]);
                    *(unsigned short*)((char*)Hs + swz(lr, gc * 2)) = ov; // stage C
                }
            }
        }
    }
    __syncthreads();

    // ---- coalesced NH writeback from LDS ----
    #pragma unroll
    for (int rnd = 0; rnd < 8; ++rnd) {
        int idx = rnd * 256 + tid;
        int r = idx >> 5, c = idx & 31;
        bf16x8 v = *(const bf16x8*)((const char*)Hs + swz(r, c * 16));
        *(bf16x8*)(NHb + ((long)b * CMAX + m0 + r) * 256 + c * 8) = v;
    }

    // ================= stage C: au gate over [X, NH] (K=512) ================
    #pragma unroll
    for (int mt = 0; mt < 4; ++mt)
        #pragma unroll
        for (int nt = 0; nt < 4; ++nt) {
            f32x4 z = {0.f, 0.f, 0.f, 0.f};
            acc[mt][nt] = z;
        }
    {
        const unsigned short* wr[4];
        #pragma unroll
        for (int nt = 0; nt < 4; ++nt) wr[nt] = WA + (long)(n0w + nt * 16 + l15) * 512;
        #pragma unroll 4
        for (int ks = 0; ks < 8; ++ks) {         // K 0..255: original X (LDS)
            int ko = ks * 32;
            bf16x8 af[4], bfr[4];
            #pragma unroll
            for (int mt = 0; mt < 4; ++mt)
                af[mt] = *(const bf16x8*)((const char*)Xs +
                         swz(mt * 16 + l15, (ko + q * 8) * 2));
            #pragma unroll
            for (int nt = 0; nt < 4; ++nt)
                bfr[nt] = *(const bf16x8*)(wr[nt] + ko + q * 8);
            #pragma unroll
            for (int mt = 0; mt < 4; ++mt)
                #pragma unroll
                for (int nt = 0; nt < 4; ++nt)
                    acc[mt][nt] = __builtin_amdgcn_mfma_f32_16x16x32_bf16(
                        af[mt], bfr[nt], acc[mt][nt], 0, 0, 0);
        }
        #pragma unroll
        for (int ks = 0; ks < 8; ++ks) {         // K 256..511: NH (LDS)
            int ko = ks * 32;
            int kw = 256 + ks * 32;
            bf16x8 af[4], bfr[4];
            #pragma unroll
            for (int mt = 0; mt < 4; ++mt) {
                int r = mt * 16 + l15;
                af[mt] = *(const bf16x8*)((const char*)Hs + swz(r, (ko + q * 8) * 2));
            }
            #pragma unroll
            for (int nt = 0; nt < 4; ++nt)
                bfr[nt] = *(const bf16x8*)(wr[nt] + kw + q * 8);
            #pragma unroll
            for (int mt = 0; mt < 4; ++mt)
                #pragma unroll
                for (int nt = 0; nt < 4; ++nt)
                    acc[mt][nt] = __builtin_amdgcn_mfma_f32_16x16x32_bf16(
                        af[mt], bfr[nt], acc[mt][nt], 0, 0, 0);
        }
        float bb[4], ww[4];
        #pragma unroll
        for (int nt = 0; nt < 4; ++nt) {
            int gc = n0w + nt * 16 + l15;
            bb[nt] = au_b1v[gc]; ww[nt] = w2v[gc];
        }
        #pragma unroll
        for (int mt = 0; mt < 4; ++mt) {
            #pragma unroll
            for (int reg = 0; reg < 4; ++reg) {
                float s = 0.f;
                #pragma unroll
                for (int nt = 0; nt < 4; ++nt)
                    s += gelu_f(acc[mt][nt][reg] + bb[nt]) * ww[nt];
                #pragma unroll
                for (int off = 1; off <= 8; off <<= 1) s += __shfl_xor(s, off);
                if (l15 == 0) rsum[wid][mt * 16 + q * 4 + reg] = s;
            }
        }
        __syncthreads();
        if (tid < 64) {
            int p = m0 + tid;
            if (p < C) {
                float z = rsum[0][tid] + rsum[1][tid] + rsum[2][tid] + rsum[3][tid] + b2s[0];
                float delta = 1.f / (1.f + expf(-z));
                float na = 0.7f * svals[b * 4096 + p] + 0.3f * delta;
                nac[(long)b * CMAX + p] = fminf(fmaxf(na, 0.f), 1.f);
            }
        }
    }
}

// ---------------- rank-256 value via binary search (shfl reduce) -------------
__global__ void __launch_bounds__(256) selectT_k(const float* __restrict__ nac,
        const int* __restrict__ cnt, float* __restrict__ T)
{
    __shared__ float v[CMAX];
    __shared__ int cs[4];
    int b = blockIdx.x, tid = threadIdx.x;
    int wid = tid >> 6, lane = tid & 63;
    int C = min(cnt[b], CMAX);
    for (int i = tid; i < CMAX; i += 256)
        v[i] = (i < C) ? nac[(long)b * CMAX + i] : -1.f;
    __syncthreads();
    float lo = 0.f, hi = 1.f;
    for (int it = 0; it < 20; ++it) {   // 1e-6 resolution << BAND_EPS
        float mid = 0.5f * (lo + hi);
        int c = 0;
        for (int i = tid; i < CMAX; i += 256) c += (v[i] >= mid) ? 1 : 0;
        #pragma unroll
        for (int off = 32; off >= 1; off >>= 1) c += __shfl_xor(c, off);
        if (lane == 0) cs[wid] = c;
        __syncthreads();
        int tot = cs[0] + cs[1] + cs[2] + cs[3];
        __syncthreads();
        if (tot >= 256) lo = mid; else hi = mid;   // uniform across threads
    }
    if (tid == 0) T[b] = lo;
}

// ---------------- compact band rows into a per-batch list ----------------
__global__ void __launch_bounds__(256) bandlist_k(const float* __restrict__ nac,
        const int* __restrict__ cnt, const float* __restrict__ Tarr,
        int* __restrict__ bandlist, int* __restrict__ bandcnt)
{
    int b = blockIdx.y;
    int C = min(cnt[b], CMAX);
    int p = blockIdx.x * 256 + threadIdx.x;
    if (p < C && fabsf(nac[(long)b * CMAX + p] - Tarr[b]) < BAND_EPS) {
        int slot = atomicAdd(&bandcnt[b], 1);
        if (slot < MAXBAND) bandlist[b * MAXBAND + slot] = p;
    }
}

// ---------------- fp32 recompute: 4 band rows per block, float4-packed W^T ---
__global__ void __launch_bounds__(256) bandfix_k(
    const float* __restrict__ hid, const int* __restrict__ sidx,
    const float* __restrict__ msgc,
    const float* __restrict__ w1Pf, const float* __restrict__ su_b1,
    const float* __restrict__ w2Pf, const float* __restrict__ su_b2,
    const float* __restrict__ ln_g, const float* __restrict__ ln_b,
    const float* __restrict__ auPf, const float* __restrict__ au_b1,
    const float* __restrict__ au_w2, const float* __restrict__ au_b2,
    const float* __restrict__ svals,
    const int* __restrict__ bandlist, const int* __restrict__ bandcnt,
    float* __restrict__ nac, unsigned short* __restrict__ NHb)
{
    int b = blockIdx.y;
    int M = min(bandcnt[b], MAXBAND);
    int base = blockIdx.x * 4;
    if (base >= M) return;
    int nact = min(M - base, 4);
    int tid = threadIdx.x;
    int wid = tid >> 6, lane = tid & 63;
    const float4* w1P = (const float4*)w1Pf;
    const float4* w2P = (const float4*)w2Pf;
    const float4* auP = (const float4*)auPf;
    __shared__ float xr[4][256];
    __shared__ float hy[4][256];
    __shared__ float nh[4][256];
    __shared__ float muS[4], rsS[4];
    __shared__ int ppS[4];
    if (tid < 4)
        ppS[tid] = (tid < nact) ? bandlist[b * MAXBAND + base + tid] : -1;
    __syncthreads();
    #pragma unroll
    for (int r = 0; r < 4; ++r) {
        int pp = ppS[r];
        xr[r][tid] = (pp >= 0) ? hid[((long)b * 4096 + sidx[b * 4096 + pp]) * 256 + tid] : 0.f;
    }
    __syncthreads();
    int n = tid;
    float acc[4];
    // ---- su1 ----
    #pragma unroll
    for (int r = 0; r < 4; ++r) acc[r] = 0.f;
    for (int k4 = 0; k4 < 64; ++k4) {
        float4 w = w1P[k4 * 256 + n];
        #pragma unroll
        for (int r = 0; r < 4; ++r) {
            float4 xv = *(const float4*)&xr[r][k4 * 4];
            acc[r] = fmaf(w.x, xv.x, acc[r]);
            acc[r] = fmaf(w.y, xv.y, acc[r]);
            acc[r] = fmaf(w.z, xv.z, acc[r]);
            acc[r] = fmaf(w.w, xv.w, acc[r]);
        }
    }
    float b1v = su_b1[n];
    #pragma unroll
    for (int r = 0; r < 4; ++r) {
        int pp = ppS[r];
        float s = acc[r] + b1v;
        if (pp >= 0 && pp < 256) s += msgc[((long)b * 256 + pp) * 256 + n];
        acc[r] = gelu_f(s);
    }
    __syncthreads();
    #pragma unroll
    for (int r = 0; r < 4; ++r) hy[r][n] = acc[r];
    __syncthreads();
    // ---- su2 ----
    #pragma unroll
    for (int r = 0; r < 4; ++r) acc[r] = 0.f;
    for (int k4 = 0; k4 < 64; ++k4) {
        float4 w = w2P[k4 * 256 + n];
        #pragma unroll
        for (int r = 0; r < 4; ++r) {
            float4 hv = *(const float4*)&hy[r][k4 * 4];
            acc[r] = fmaf(w.x, hv.x, acc[r]);
            acc[r] = fmaf(w.y, hv.y, acc[r]);
            acc[r] = fmaf(w.z, hv.z, acc[r]);
            acc[r] = fmaf(w.w, hv.w, acc[r]);
        }
    }
    __syncthreads();
    float b2v = su_b2[n];
    #pragma unroll
    for (int r = 0; r < 4; ++r) hy[r][n] = acc[r] + b2v;
    __syncthreads();
    // LN stats: wave wid handles row wid
    {
        int r = wid;
        float4 yv = *(const float4*)&hy[r][lane * 4];
        float s = yv.x + yv.y + yv.z + yv.w;
        float s2 = yv.x * yv.x + yv.y * yv.y + yv.z * yv.z + yv.w * yv.w;
        #pragma unroll
        for (int off = 32; off >= 1; off >>= 1) {
            s += __shfl_xor(s, off);
            s2 += __shfl_xor(s2, off);
        }
        if (lane == 0) {
            float mu = s * (1.f / 256.f);
            float var = s2 * (1.f / 256.f) - mu * mu;
            muS[r] = mu; rsS[r] = rsqrtf(var + 1e-5f);
        }
    }
    __syncthreads();
    float gv = ln_g[n], ev = ln_b[n];
    #pragma unroll
    for (int r = 0; r < 4; ++r) {
        float o = (hy[r][n] - muS[r]) * rsS[r] * gv + ev;
        nh[r][n] = o;
        if (ppS[r] >= 0) NHb[((long)b * CMAX + ppS[r]) * 256 + n] = f2bf(o);
    }
    __syncthreads();
    // ---- au ----
    #pragma unroll
    for (int r = 0; r < 4; ++r) acc[r] = 0.f;
    for (int k4 = 0; k4 < 64; ++k4) {
        float4 w = auP[k4 * 256 + n];
        #pragma unroll
        for (int r = 0; r < 4; ++r) {
            float4 xv = *(const float4*)&xr[r][k4 * 4];
            acc[r] = fmaf(w.x, xv.x, acc[r]);
            acc[r] = fmaf(w.y, xv.y, acc[r]);
            acc[r] = fmaf(w.z, xv.z, acc[r]);
            acc[r] = fmaf(w.w, xv.w, acc[r]);
        }
    }
    for (int k4 = 64; k4 < 128; ++k4) {
        float4 w = auP[k4 * 256 + n];
        #pragma unroll
        for (int r = 0; r < 4; ++r) {
            float4 hv = *(const float4*)&nh[r][(k4 - 64) * 4];
            acc[r] = fmaf(w.x, hv.x, acc[r]);
            acc[r] = fmaf(w.y, hv.y, acc[r]);
            acc[r] = fmaf(w.z, hv.z, acc[r]);
            acc[r] = fmaf(w.w, hv.w, acc[r]);
        }
    }
    float ab = au_b1[n], wv2 = au_w2[n];
    __syncthreads();
    #pragma unroll
    for (int r = 0; r < 4; ++r) hy[r][n] = gelu_f(acc[r] + ab) * wv2;
    __syncthreads();
    {
        int r = wid;
        float4 gvv = *(const float4*)&hy[r][lane * 4];
        float s = gvv.x + gvv.y + gvv.z + gvv.w;
        #pragma unroll
        for (int off = 32; off >= 1; off >>= 1) s += __shfl_xor(s, off);
        if (lane == 0 && ppS[r] >= 0) {
            float z = s + au_b2[0];
            float delta = 1.f / (1.f + expf(-z));
            float na = 0.7f * svals[b * 4096 + ppS[r]] + 0.3f * delta;
            nac[(long)b * CMAX + ppS[r]] = fminf(fmaxf(na, 0.f), 1.f);
        }
    }
}

// ---------------- scatter outputs ----------------
__global__ void __launch_bounds__(64) scatter_k(const float* __restrict__ selv,
        const int* __restrict__ selo, const int* __restrict__ selp,
        const unsigned short* __restrict__ NHb, float* __restrict__ out)
{
    int b = blockIdx.x >> 8, j = blockIdx.x & 255, t = threadIdx.x;
    int orig = selo[b * 256 + j];
    int p = selp[b * 256 + j];
    if (t == 0) out[b * 4096 + orig] = selv[b * 256 + j];
    const ushort4* src = (const ushort4*)(NHb + ((long)b * CMAX + p) * 256);
    ushort4 s = src[t];
    float4 o = make_float4(bf2f(s.x), bf2f(s.y), bf2f(s.z), bf2f(s.w));
    *(float4*)(out + 131072 + ((long)(b * 4096 + orig)) * 256 + t * 4) = o;
}

extern "C" void kernel_launch(void* const* d_in, const int* in_sizes, int n_in,
                              void* d_out, int out_size, void* d_ws, size_t ws_size,
                              hipStream_t stream)
{
    const float* act   = (const float*)d_in[0];
    const float* hid   = (const float*)d_in[1];
    const float* wi    = (const float*)d_in[2];
    const float* bi    = (const float*)d_in[3];
    const float* wo    = (const float*)d_in[4];
    const float* bo    = (const float*)d_in[5];
    const float* su_w1 = (const float*)d_in[6];
    const float* su_b1 = (const float*)d_in[7];
    const float* su_w2 = (const float*)d_in[8];
    const float* su_b2 = (const float*)d_in[9];
    const float* au_w1 = (const float*)d_in[10];
    const float* au_b1 = (const float*)d_in[11];
    const float* au_w2 = (const float*)d_in[12];
    const float* au_b2 = (const float*)d_in[13];
    const float* ln_g  = (const float*)d_in[14];
    const float* ln_b  = (const float*)d_in[15];
    float* out = (float*)d_out;

    char* ws = (char*)d_ws;
    size_t off = 0;
    auto alloc = [&](size_t bytes) {
        size_t o = off; off += (bytes + 255) & ~(size_t)255; return o;
    };
    float* svals = (float*)(ws + alloc((size_t)32 * 4096 * 4));
    int*   sidx  = (int*)  (ws + alloc((size_t)32 * 4096 * 4));
    int*   cnt   = (int*)  (ws + alloc(256));
    float* qkv   = (float*)(ws + alloc((size_t)32 * 256 * 768 * 4));
    float* Sb    = (float*)(ws + alloc((size_t)32 * 4 * 256 * 256 * 4));
    float* Ob    = (float*)(ws + alloc((size_t)32 * 256 * 256 * 4));
    float* MSGC  = (float*)(ws + alloc((size_t)32 * 256 * 256 * 4));
    float* selv  = (float*)(ws + alloc((size_t)32 * 256 * 4));
    int*   selo  = (int*)  (ws + alloc((size_t)32 * 256 * 4));
    int*   selp  = (int*)  (ws + alloc((size_t)32 * 256 * 4));
    unsigned short* swb1 = (unsigned short*)(ws + alloc((size_t)256 * 512 * 2));
    unsigned short* swb2 = (unsigned short*)(ws + alloc((size_t)256 * 256 * 2));
    unsigned short* awb1 = (unsigned short*)(ws + alloc((size_t)256 * 512 * 2));
    float* w1P = (float*)(ws + alloc((size_t)256 * 256 * 4));
    float* w2P = (float*)(ws + alloc((size_t)256 * 256 * 4));
    float* auP = (float*)(ws + alloc((size_t)512 * 256 * 4));
    unsigned short* Xb   = (unsigned short*)(ws + alloc((size_t)32 * CMAX * 256 * 2));
    unsigned short* NHb  = (unsigned short*)(ws + alloc((size_t)32 * CMAX * 256 * 2));
    float* nac = (float*)(ws + alloc((size_t)32 * CMAX * 4));
    float* Tb  = (float*)(ws + alloc(128));
    int* bandl = (int*)(ws + alloc((size_t)32 * MAXBAND * 4));
    int* bandc = (int*)(ws + alloc(128));

    // 0. zero band counters
    hipMemsetAsync(bandc, 0, 32 * sizeof(int), stream);
    // 1. zero outputs
    fill0_k<<<2048, 256, 0, stream>>>((float4*)out, (long)out_size / 4);
    // 2. radix-select activations (deterministic index-order compaction)
    topk1_k<<<32, 256, 0, stream>>>(act, svals, sidx, cnt);
    // 3. weight conversion + packed fp32 transposes (single launch)
    prep_k<<<768, 256, 0, stream>>>(su_w1, su_w2, au_w1, swb1, swb2, awb1,
                                    w1P, w2P, auP);
    // 4. gather + bf16 candidate rows
    gatherX_k<<<dim3(CMAX / 4, 32), 256, 0, stream>>>(hid, sidx, cnt, Xb);
    // 5. qkv = gather(hidden) @ wi^T + bi  (64x128 tiles -> 768 blocks)
    gemm_k<64, 128, 8, 4, true, true, 1><<<dim3(6, 4, 32), 256, 0, stream>>>(
        hid, 256, (long)4096 * 256, 0, 1,
        wi, 256, 0, 0, 1,
        qkv, 768, (long)256 * 768, 0, 1,
        256, bi, nullptr, 0, sidx, 4096, 0.f);
    // 6. P = softmax(q @ k^T / 8)  (32x256 tiles -> 1024 blocks, EPI=4)
    gemm_k<32, 256, 4, 8, true, false, 4><<<dim3(1, 8, 128), 256, 0, stream>>>(
        qkv, 768, 196608, 64, 4,
        qkv + 256, 768, 196608, 64, 4,
        Sb, 256, 65536, 0, 1,
        64, nullptr, nullptr, 0, nullptr, 0, 0.125f);
    // 7. O = P @ V
    gemm_k<64, 64, 4, 4, false, false, 0><<<dim3(1, 4, 128), 256, 0, stream>>>(
        Sb, 256, 65536, 0, 1,
        qkv + 512, 768, 196608, 64, 4,
        Ob, 256, 65536, 64, 4,
        256, nullptr, nullptr, 0, nullptr, 0, 0.f);
    // 8. MSGC = ((O @ wo^T + bo) * tv) @ W1b^T  -- fused
    msgc_k<<<dim3(8, 32), 256, 0, stream>>>(Ob, wo, bo, su_w1, svals, MSGC);
    // 9. fused candidate-row MLP (su1 -> su2+LN -> au), bf16 MFMA + LDS
    fused_mlp_k<<<dim3(CMAX / 64, 32), 256, 0, stream>>>(Xb, swb1, swb2, awb1,
        su_b1, MSGC, su_b2, ln_g, ln_b, au_b1, au_w2, au_b2, svals, cnt,
        NHb, nac);
    // 10. rank-256 value per batch (band center)
    selectT_k<<<32, 256, 0, stream>>>(nac, cnt, Tb);
    // 11a. compact band rows
    bandlist_k<<<dim3(CMAX / 256, 32), 256, 0, stream>>>(nac, cnt, Tb, bandl, bandc);
    // 11b. fp32 recompute of boundary-band rows, 4 rows/block, packed W^T
    bandfix_k<<<dim3(MAXBAND / 4, 32), 256, 0, stream>>>(hid, sidx, MSGC,
        w1P, su_b1, w2P, su_b2, ln_g, ln_b, auP, au_b1, au_w2, au_b2,
        svals, bandl, bandc, nac, NHb);
    // 12. exact top-256 selection over corrected new activations
    topk2_k<<<32, 256, 0, stream>>>(nac, sidx, cnt, selv, selo, selp);
    // 13. scatter selected rows
    scatter_k<<<8192, 64, 0, stream>>>(selv, selo, selp, NHb, out);
}

// Round 11
// 671.902 us; speedup vs baseline: 1.0687x; 1.0187x over previous
//
#include <hip/hip_runtime.h>

// NeuronInteraction: B=32, N=4096, D=256, H=4, hd=64, MSG_K=256, k=256
// Pipeline:
//  front_k(fill0 + topk1-deterministic + prep, one dispatch) -> gatherX ->
//  qkv GEMM (64x128) -> S+softmax GEMM (32x256, EPI=4) -> PV GEMM -> msgc_k ->
//  FUSED bf16 MFMA MLP -> selband_k (selectT + bandlist fused) -> bandfix ->
//  topk2 -> scatter.
// R10 post-mortem: grid retiling gave +5.5us (684.5, best). Remaining ~530us
// is 12 small launches; per-kernel tuning is single-digit us. R11: merge
// independent front kernels (fill0 BW-bound + topk1 latency-bound + prep)
// into ONE dispatch (co-scheduling + 2 fewer launches) and fuse the
// producer/consumer pair selectT+bandlist (1 fewer launch + no bandc memset).
// Numerics identical; bandl order varies as before (bandfix is keyed-write
// order-invariant). Deterministic topk1 retained (replay-flip insurance).
// BAND_EPS=0.004: bf16-path na error max-stat ~1.1e-4 (36x margin).

constexpr int KC = 32;
constexpr int CMAX = 2304;           // E[cands]=2012, sigma~32 -> +9 sigma
constexpr float BAND_EPS = 0.004f;
constexpr int MAXBAND = 512;         // E[band]~47 -> 10x margin

typedef short bf16x8 __attribute__((ext_vector_type(8)));
typedef float f32x4 __attribute__((ext_vector_type(4)));

__device__ __forceinline__ float gelu_f(float x) {
    return 0.5f * x * (1.0f + erff(x * 0.70710678118654752440f));
}
__device__ __forceinline__ unsigned short f2bf(float f) {
    unsigned u = __float_as_uint(f);
    return (unsigned short)((u + 0x7fffu + ((u >> 16) & 1u)) >> 16);
}
__device__ __forceinline__ float bf2f(unsigned short h) {
    return __uint_as_float(((unsigned)h) << 16);
}
// XOR swizzle for a [R][256] bf16 LDS tile (row stride 512B): spreads the
// 16B granules of 8 consecutive rows across distinct banks so that
// ds_read_b128 of {rows r..r+15, same col-chunk} is ~2-way (free, m136).
__device__ __forceinline__ int swz(int row, int byteInRow) {
    return (row << 9) + (byteInRow ^ ((row & 7) << 4));
}

// ---------------- front: fill0 + deterministic topk1 + prep (one dispatch) ---
// blocks 0..2047: zero output. 2048..2079: topk1 (b = blk-2048).
// 2080..2847: prep (rel = blk-2080; 0..511 bf16 convert, 512..575 w1P,
// 576..639 w2P, 640..767 auP).
__global__ void __launch_bounds__(256) front_k(
        float4* __restrict__ outp, long n4,
        const float* __restrict__ act,
        float* __restrict__ svals, int* __restrict__ sidx, int* __restrict__ cnt,
        const float* __restrict__ s1, const float* __restrict__ s2,
        const float* __restrict__ a1,
        unsigned short* __restrict__ o1, unsigned short* __restrict__ o2,
        unsigned short* __restrict__ o3,
        float* __restrict__ w1P, float* __restrict__ w2P, float* __restrict__ auP)
{
    int blk = blockIdx.x, tid = threadIdx.x;
    if (blk < 2048) {
        // ---- zero-fill output (grid-stride over 2048 virtual blocks) ----
        long i = (long)blk * 256 + tid;
        long stride = (long)2048 * 256;
        float4 z = make_float4(0.f, 0.f, 0.f, 0.f);
        for (; i < n4; i += stride) outp[i] = z;
        return;
    }
    if (blk < 2080) {
        // ---- topk1: radix threshold + deterministic index-order compaction --
        __shared__ int cs[4];
        int b = blk - 2048;
        int wid = tid >> 6, lane = tid & 63;
        unsigned v[16];
        #pragma unroll
        for (int s = 0; s < 16; ++s)
            v[s] = __float_as_uint(act[b * 4096 + s * 256 + tid]); // >=0 monotone

        auto reduce4 = [&](int c) -> int {
            #pragma unroll
            for (int off = 32; off >= 1; off >>= 1) c += __shfl_xor(c, off);
            if (lane == 0) cs[wid] = c;
            __syncthreads();
            int tot = cs[0] + cs[1] + cs[2] + cs[3];
            __syncthreads();
            return tot;
        };
        auto countGE = [&](unsigned thr) -> int {
            int c = 0;
            #pragma unroll
            for (int s = 0; s < 16; ++s) c += (v[s] >= thr) ? 1 : 0;
            return reduce4(c);
        };
        auto countEqLt = [&](unsigned vs, int icut) -> int {
            int c = 0;
            #pragma unroll
            for (int s = 0; s < 16; ++s)
                c += (v[s] == vs && (s * 256 + tid) < icut) ? 1 : 0;
            return reduce4(c);
        };

        unsigned vstar = 0;
        for (int bit = 31; bit >= 0; --bit) {
            unsigned cand = vstar | (1u << bit);
            if (countGE(cand) >= 256) vstar = cand;
        }
        int cgt = countGE(vstar + 1);
        int needed = 256 - cgt;
        int icut = 4096;
        if (countEqLt(vstar, 4096) > needed) {
            int lo = 0, hi = 4096;
            for (int it = 0; it < 12; ++it) {
                int mid = (lo + hi) >> 1;
                if (countEqLt(vstar, mid) <= needed) lo = mid; else hi = mid;
            }
            icut = lo;
        }
        float th = __uint_as_float(vstar) - 0.4288f;  // > 3/7 margin
        int basePacked = 0;   // low16: top base, high16: rest base (uniform)
        for (int s = 0; s < 16; ++s) {
            int i = s * 256 + tid;
            unsigned vb = v[s];
            float f = __uint_as_float(vb);
            bool top = (vb > vstar) || (vb == vstar && i < icut);
            bool rest = (!top) && (f >= th);
            int flag = (top ? 1 : 0) | (rest ? (1 << 16) : 0);
            int x = flag;
            #pragma unroll
            for (int off = 1; off < 64; off <<= 1) {  // inclusive wave scan
                int n = __shfl_up(x, off);
                if (lane >= off) x += n;
            }
            if (lane == 63) cs[wid] = x;
            __syncthreads();
            int waveOff = 0;
            #pragma unroll
            for (int w = 0; w < 4; ++w) if (w < wid) waveOff += cs[w];
            int tot = cs[0] + cs[1] + cs[2] + cs[3];
            int excl = x - flag + waveOff;            // exclusive (packed)
            if (top) {
                int slot = (basePacked & 0xffff) + (excl & 0xffff);
                sidx[b * 4096 + slot] = i;
                svals[b * 4096 + slot] = f;
            } else if (rest) {
                int slot = 256 + (basePacked >> 16) + (excl >> 16);
                if (slot < CMAX) {
                    sidx[b * 4096 + slot] = i;
                    svals[b * 4096 + slot] = f;
                }
            }
            basePacked += tot;
            __syncthreads();   // protect cs reuse next round
        }
        if (tid == 0) cnt[b] = min(256 + (basePacked >> 16), CMAX);
        return;
    }
    // ---- prep: bf16 convert + packed fp32 transposes ----
    int rel0 = blk - 2080;
    if (rel0 < 512) {
        int i = rel0 * 256 + tid;
        o1[i] = f2bf(s1[i]);
        o3[i] = f2bf(a1[i]);
        if (i < 65536) o2[i] = f2bf(s2[i]);
        return;
    }
    const float* src; float* dst; int ld, ktiles, rel;
    if (rel0 < 576) { rel = rel0 - 512; src = s1; ld = 512; dst = w1P; ktiles = 8; }
    else if (rel0 < 640) { rel = rel0 - 576; src = s2; ld = 256; dst = w2P; ktiles = 8; }
    else { rel = rel0 - 640; src = a1; ld = 512; dst = auP; ktiles = 16; }
    int k0 = (rel % ktiles) * 32, n0 = (rel / ktiles) * 32;
    __shared__ float t[32][33];
    int tx = tid & 31, ty = tid >> 5;
    #pragma unroll
    for (int yy = 0; yy < 4; ++yy) {
        int nl = ty * 4 + yy;
        t[nl][tx] = src[(long)(n0 + nl) * ld + k0 + tx];
    }
    __syncthreads();
    #pragma unroll
    for (int yy = 0; yy < 4; ++yy) {
        int k = k0 + ty * 4 + yy;
        dst[(long)(k >> 2) * 1024 + (n0 + tx) * 4 + (k & 3)] = t[tx][ty * 4 + yy];
    }
}

// ---------------- top-k #2: radix threshold selection over candidates --------
// (atomic slot order is fine here: each output entry depends only on itself)
__global__ void __launch_bounds__(256) topk2_k(const float* __restrict__ newact,
        const int* __restrict__ sidx, const int* __restrict__ cnt,
        float* __restrict__ selv, int* __restrict__ selo, int* __restrict__ selp)
{
    __shared__ int cs[4];
    __shared__ int sSel;
    int b = blockIdx.x, tid = threadIdx.x;
    int wid = tid >> 6, lane = tid & 63;
    int C = min(cnt[b], CMAX);
    unsigned v[9];
    int org[9];
    #pragma unroll
    for (int s = 0; s < 9; ++s) {
        int p = s * 256 + tid;
        bool ok = (p < C && p < CMAX);
        v[s] = ok ? __float_as_uint(newact[(long)b * CMAX + p]) : 0u;
        org[s] = ok ? sidx[b * 4096 + p] : 0x7FFFFFFF;
    }
    auto reduce4 = [&](int c) -> int {
        #pragma unroll
        for (int off = 32; off >= 1; off >>= 1) c += __shfl_xor(c, off);
        if (lane == 0) cs[wid] = c;
        __syncthreads();
        int tot = cs[0] + cs[1] + cs[2] + cs[3];
        __syncthreads();
        return tot;
    };
    auto countGE = [&](unsigned thr) -> int {
        int c = 0;
        #pragma unroll
        for (int s = 0; s < 9; ++s) c += (v[s] >= thr) ? 1 : 0;
        return reduce4(c);
    };
    auto countEqLt = [&](unsigned vs, int icut) -> int {
        int c = 0;
        #pragma unroll
        for (int s = 0; s < 9; ++s) c += (v[s] == vs && org[s] < icut) ? 1 : 0;
        return reduce4(c);
    };

    unsigned vstar = 0;
    for (int bit = 31; bit >= 0; --bit) {
        unsigned cand = vstar | (1u << bit);
        if (countGE(cand) >= 256) vstar = cand;
    }
    int cgt = countGE(vstar + 1);
    int needed = 256 - cgt;
    int icut = 4096;
    if (countEqLt(vstar, 4096) > needed) {
        int lo = 0, hi = 4096;
        for (int it = 0; it < 12; ++it) {
            int mid = (lo + hi) >> 1;
            if (countEqLt(vstar, mid) <= needed) lo = mid; else hi = mid;
        }
        icut = lo;
    }
    if (tid == 0) sSel = 0;
    __syncthreads();
    #pragma unroll
    for (int s = 0; s < 9; ++s) {
        unsigned vb = v[s];
        bool sel = (vb > vstar) || (vb == vstar && org[s] < icut);
        if (sel) {
            int slot = atomicAdd(&sSel, 1);
            selv[b * 256 + slot] = __uint_as_float(vb);
            selo[b * 256 + slot] = org[s];
            selp[b * 256 + slot] = s * 256 + tid;
        }
    }
}

// ---------------- generic fp32 tiled GEMM (attention chain) ----------------
// EPI: 0 none, 1 +bias, 2 +bias*rowscale, 3 *cscale, 4 row-softmax(cscale)
template<int TM, int TN, int RM, int RN, bool BT, bool GATHER, int EPI>
__global__ void __launch_bounds__(256) gemm_k(
    const float* __restrict__ A, int lda, long sA1, long sA2, int divA,
    const float* __restrict__ B, int ldb, long sB1, long sB2, int divB,
    float* __restrict__ C, int ldc, long sC1, long sC2, int divC,
    int K, const float* __restrict__ bias, const float* __restrict__ rowscale,
    long rsStride, const int* __restrict__ gmap, long gmapStride, float cscale)
{
    constexpr int TX = TN / RN, TY = TM / RM;
    static_assert(TX * TY == 256, "block must be 256 threads");
    static_assert(EPI != 4 || TX == 32, "softmax epilogue needs TX==32");
    static_assert(RM >= 4 && RN >= 4, "float4 register reads need RM,RN >= 4");
    __shared__ float As[KC][TM + 4];
    __shared__ float Bs[KC][TN + 4];
    int z = blockIdx.z;
    const float* Ab = A + (long)(z / divA) * sA1 + (long)(z % divA) * sA2;
    const float* Bb = B + (long)(z / divB) * sB1 + (long)(z % divB) * sB2;
    float* Cb = C + (long)(z / divC) * sC1 + (long)(z % divC) * sC2;
    int m0 = blockIdx.y * TM, n0 = blockIdx.x * TN;
    int tid = threadIdx.x;
    int tx = tid % TX, ty = tid / TX;
    float acc[RM][RN];
    #pragma unroll
    for (int i = 0; i < RM; ++i)
        #pragma unroll
        for (int j = 0; j < RN; ++j) acc[i][j] = 0.f;

    for (int k0 = 0; k0 < K; k0 += KC) {
        __syncthreads();
        #pragma unroll
        for (int u = 0; u < (TM * KC) / 1024; ++u) {
            int idx = tid + u * 256;
            int m = idx / (KC / 4), k4 = idx % (KC / 4);
            int row = m0 + m;
            long grow = GATHER ? (long)gmap[(long)z * gmapStride + row] : (long)row;
            float4 v = *(const float4*)(Ab + grow * lda + k0 + k4 * 4);
            As[k4 * 4 + 0][m] = v.x; As[k4 * 4 + 1][m] = v.y;
            As[k4 * 4 + 2][m] = v.z; As[k4 * 4 + 3][m] = v.w;
        }
        if (BT) {
            #pragma unroll
            for (int u = 0; u < (TN * KC) / 1024; ++u) {
                int idx = tid + u * 256;
                int n = idx / (KC / 4), k4 = idx % (KC / 4);
                float4 v = *(const float4*)(Bb + (long)(n0 + n) * ldb + k0 + k4 * 4);
                Bs[k4 * 4 + 0][n] = v.x; Bs[k4 * 4 + 1][n] = v.y;
                Bs[k4 * 4 + 2][n] = v.z; Bs[k4 * 4 + 3][n] = v.w;
            }
        } else {
            #pragma unroll
            for (int u = 0; u < (TN * KC) / 1024; ++u) {
                int idx = tid + u * 256;
                int k = idx / (TN / 4), n4 = idx % (TN / 4);
                float4 v = *(const float4*)(Bb + (long)(k0 + k) * ldb + n0 + n4 * 4);
                *(float4*)&Bs[k][n4 * 4] = v;
            }
        }
        __syncthreads();
        #pragma unroll
        for (int k = 0; k < KC; ++k) {
            float av[RM], bv[RN];
            #pragma unroll
            for (int i = 0; i < RM; i += 4) {
                float4 t = *(const float4*)&As[k][ty * RM + i];
                av[i] = t.x; av[i + 1] = t.y; av[i + 2] = t.z; av[i + 3] = t.w;
            }
            #pragma unroll
            for (int j = 0; j < RN; j += 4) {
                float4 t = *(const float4*)&Bs[k][tx * RN + j];
                bv[j] = t.x; bv[j + 1] = t.y; bv[j + 2] = t.z; bv[j + 3] = t.w;
            }
            #pragma unroll
            for (int i = 0; i < RM; ++i)
                #pragma unroll
                for (int j = 0; j < RN; ++j)
                    acc[i][j] = fmaf(av[i], bv[j], acc[i][j]);
        }
    }
    if (EPI == 4) {
        // fused row softmax: block owns the FULL row (n0==0, TN==K-range).
        // Row r is held by the 32 same-ty threads; they sit in one 32-lane
        // half-wave (tid = ty*32+tx) so shfl_xor(<=16) reduces exactly over r.
        #pragma unroll
        for (int i = 0; i < RM; ++i) {
            float m = -1e30f;
            #pragma unroll
            for (int j = 0; j < RN; ++j) {
                acc[i][j] *= cscale;
                m = fmaxf(m, acc[i][j]);
            }
            #pragma unroll
            for (int off = 16; off >= 1; off >>= 1) m = fmaxf(m, __shfl_xor(m, off));
            float s = 0.f;
            #pragma unroll
            for (int j = 0; j < RN; ++j) {
                acc[i][j] = expf(acc[i][j] - m);
                s += acc[i][j];
            }
            #pragma unroll
            for (int off = 16; off >= 1; off >>= 1) s += __shfl_xor(s, off);
            float inv = 1.f / s;
            #pragma unroll
            for (int j = 0; j < RN; ++j) acc[i][j] *= inv;
        }
    }
    #pragma unroll
    for (int i = 0; i < RM; ++i) {
        int gm = m0 + ty * RM + i;
        float rs = 1.f;
        if (EPI == 2) rs = rowscale[(long)z * rsStride + gm];
        #pragma unroll
        for (int j = 0; j < RN; j += 4) {
            int gn = n0 + tx * RN + j;
            float4 v = make_float4(acc[i][j], acc[i][j + 1], acc[i][j + 2], acc[i][j + 3]);
            if (EPI == 1 || EPI == 2) {
                float4 bb = *(const float4*)(bias + gn);
                v.x += bb.x; v.y += bb.y; v.z += bb.z; v.w += bb.w;
            }
            if (EPI == 2) { v.x *= rs; v.y *= rs; v.z *= rs; v.w *= rs; }
            if (EPI == 3) { v.x *= cscale; v.y *= cscale; v.z *= cscale; v.w *= cscale; }
            *(float4*)(Cb + (long)gm * ldc + gn) = v;
        }
    }
}

// ---------------- fused: MSGC = ((O@wo^T+bo)*tv) @ W1b^T ---------
// Block = 32 MSG rows x 256 cols; MSG tile lives in LDS (never hits global).
__global__ void __launch_bounds__(256) msgc_k(
    const float* __restrict__ Ob,     // [32][256][256]
    const float* __restrict__ wo,     // [256][256]
    const float* __restrict__ bo,     // [256]
    const float* __restrict__ su_w1,  // [256][512]; cols 256.. = W1b
    const float* __restrict__ svals,  // tv = svals[b*4096 + row]
    float* __restrict__ MSGC)         // [32][256][256]
{
    constexpr int TM = 32, TN = 256, RM = 4, RN = 8;
    constexpr int TX = TN / RN;  // 32
    __shared__ float As[KC][TM + 4];
    __shared__ float Bs[KC][TN + 4];
    __shared__ float Ms[TM][TN + 4];  // MSG tile [m][k]
    int b = blockIdx.y;
    int m0 = blockIdx.x * TM;
    int tid = threadIdx.x;
    int tx = tid % TX, ty = tid / TX;
    const float* Ab = Ob + (long)b * 65536;
    float acc[RM][RN];

    // ---- phase 1: MSG = O @ wo^T + bo, scaled by tv ----
    #pragma unroll
    for (int i = 0; i < RM; ++i)
        #pragma unroll
        for (int j = 0; j < RN; ++j) acc[i][j] = 0.f;
    for (int k0 = 0; k0 < 256; k0 += KC) {
        __syncthreads();
        {   // stage A: 32 rows x KC  (1 float4/thread)
            int m = tid / (KC / 4), k4 = tid % (KC / 4);
            float4 v = *(const float4*)(Ab + (long)(m0 + m) * 256 + k0 + k4 * 4);
            As[k4 * 4 + 0][m] = v.x; As[k4 * 4 + 1][m] = v.y;
            As[k4 * 4 + 2][m] = v.z; As[k4 * 4 + 3][m] = v.w;
        }
        #pragma unroll
        for (int u = 0; u < 8; ++u) {  // stage B (wo, BT): 256 n x KC
            int idx = tid + u * 256;
            int n = idx / (KC / 4), k4 = idx % (KC / 4);
            float4 v = *(const float4*)(wo + (long)n * 256 + k0 + k4 * 4);
            Bs[k4 * 4 + 0][n] = v.x; Bs[k4 * 4 + 1][n] = v.y;
            Bs[k4 * 4 + 2][n] = v.z; Bs[k4 * 4 + 3][n] = v.w;
        }
        __syncthreads();
        #pragma unroll
        for (int k = 0; k < KC; ++k) {
            float av[RM], bv[RN];
            float4 ta = *(const float4*)&As[k][ty * RM];
            av[0] = ta.x; av[1] = ta.y; av[2] = ta.z; av[3] = ta.w;
            #pragma unroll
            for (int j = 0; j < RN; j += 4) {
                float4 t = *(const float4*)&Bs[k][tx * RN + j];
                bv[j] = t.x; bv[j + 1] = t.y; bv[j + 2] = t.z; bv[j + 3] = t.w;
            }
            #pragma unroll
            for (int i = 0; i < RM; ++i)
                #pragma unroll
                for (int j = 0; j < RN; ++j)
                    acc[i][j] = fmaf(av[i], bv[j], acc[i][j]);
        }
    }
    __syncthreads();   // As/Bs reuse below; also orders Ms writes
    #pragma unroll
    for (int i = 0; i < RM; ++i) {
        int gm = m0 + ty * RM + i;
        float tv = svals[b * 4096 + gm];
        #pragma unroll
        for (int j = 0; j < RN; j += 4) {
            int gn = tx * RN + j;
            float4 bb = *(const float4*)(bo + gn);
            float4 v;
            v.x = (acc[i][j + 0] + bb.x) * tv;
            v.y = (acc[i][j + 1] + bb.y) * tv;
            v.z = (acc[i][j + 2] + bb.z) * tv;
            v.w = (acc[i][j + 3] + bb.w) * tv;
            *(float4*)&Ms[ty * RM + i][gn] = v;
        }
    }

    // ---- phase 2: MSGC = MSG @ W1b^T ----
    #pragma unroll
    for (int i = 0; i < RM; ++i)
        #pragma unroll
        for (int j = 0; j < RN; ++j) acc[i][j] = 0.f;
    const float* W1b = su_w1 + 256;
    for (int k0 = 0; k0 < 256; k0 += KC) {
        __syncthreads();
        #pragma unroll
        for (int u = 0; u < 8; ++u) {  // stage B (W1b, BT, ldb=512)
            int idx = tid + u * 256;
            int n = idx / (KC / 4), k4 = idx % (KC / 4);
            float4 v = *(const float4*)(W1b + (long)n * 512 + k0 + k4 * 4);
            Bs[k4 * 4 + 0][n] = v.x; Bs[k4 * 4 + 1][n] = v.y;
            Bs[k4 * 4 + 2][n] = v.z; Bs[k4 * 4 + 3][n] = v.w;
        }
        __syncthreads();
        #pragma unroll
        for (int k = 0; k < KC; ++k) {
            float av[RM], bv[RN];
            #pragma unroll
            for (int i = 0; i < RM; ++i)
                av[i] = Ms[ty * RM + i][k0 + k];   // broadcast reads
            #pragma unroll
            for (int j = 0; j < RN; j += 4) {
                float4 t = *(const float4*)&Bs[k][tx * RN + j];
                bv[j] = t.x; bv[j + 1] = t.y; bv[j + 2] = t.z; bv[j + 3] = t.w;
            }
            #pragma unroll
            for (int i = 0; i < RM; ++i)
                #pragma unroll
                for (int j = 0; j < RN; ++j)
                    acc[i][j] = fmaf(av[i], bv[j], acc[i][j]);
        }
    }
    float* Cb = MSGC + (long)b * 65536;
    #pragma unroll
    for (int i = 0; i < RM; ++i) {
        int gm = m0 + ty * RM + i;
        #pragma unroll
        for (int j = 0; j < RN; j += 4) {
            int gn = tx * RN + j;
            float4 v = make_float4(acc[i][j], acc[i][j + 1], acc[i][j + 2], acc[i][j + 3]);
            *(float4*)(Cb + (long)gm * 256 + gn) = v;
        }
    }
}

// ---------------- gather candidate rows -> bf16 [B][CMAX][256] ----------------
__global__ void __launch_bounds__(256) gatherX_k(const float* __restrict__ hid,
        const int* __restrict__ sidx, const int* __restrict__ cnt,
        unsigned short* __restrict__ Xb)
{
    int b = blockIdx.y;
    int C = min(cnt[b], CMAX);
    int p = blockIdx.x * 4 + (threadIdx.x >> 6);
    int lane = threadIdx.x & 63;
    unsigned short* dst = Xb + ((long)b * CMAX + p) * 256 + lane * 4;
    if (p < C) {
        int row = sidx[b * 4096 + p];
        float4 v = *(const float4*)(hid + ((long)b * 4096 + row) * 256 + lane * 4);
        ushort4 o; o.x = f2bf(v.x); o.y = f2bf(v.y); o.z = f2bf(v.z); o.w = f2bf(v.w);
        *(ushort4*)dst = o;
    } else {
        ushort4 z; z.x = 0; z.y = 0; z.z = 0; z.w = 0;
        *(ushort4*)dst = z;
    }
}

// ---------------- FUSED bf16 MFMA MLP: su1 -> su2+LN -> au in one kernel -----
// (R4 variant, measured ~153us.) Block = 64 rows x 256 cols, 4 waves.
// X staged once into swizzled LDS (reused stages A+C); H1/NH in 2nd tile.
__global__ void __launch_bounds__(256, 2) fused_mlp_k(
    const unsigned short* __restrict__ Xb,
    const unsigned short* __restrict__ W1,   // [256][512] bf16, K used: 0..255
    const unsigned short* __restrict__ W2,   // [256][256] bf16
    const unsigned short* __restrict__ WA,   // [256][512] bf16, full K
    const float* __restrict__ su_b1v, const float* __restrict__ msgc,
    const float* __restrict__ su_b2v,
    const float* __restrict__ lng, const float* __restrict__ lnb,
    const float* __restrict__ au_b1v,
    const float* __restrict__ w2v, const float* __restrict__ b2s,
    const float* __restrict__ svals, const int* __restrict__ cnt,
    unsigned short* __restrict__ NHb, float* __restrict__ nac)
{
    int b = blockIdx.y;
    int C = min(cnt[b], CMAX);
    int m0 = blockIdx.x * 64;
    if (m0 >= C) return;
    int tid = threadIdx.x;
    int wid = tid >> 6;
    int lane = tid & 63;
    int l15 = lane & 15;
    int q = lane >> 4;
    int n0w = wid * 64;

    __shared__ __align__(16) unsigned short Xs[64 * 256]; // swizzled X tile
    __shared__ __align__(16) unsigned short Hs[64 * 256]; // swizzled H1/NH tile
    __shared__ float rsum[4][64];
    __shared__ float rsq[4][64];
    __shared__ float rmu[64], rrs[64];

    const unsigned short* Ab = Xb + ((long)b * CMAX + m0) * 256;

    #pragma unroll
    for (int rnd = 0; rnd < 8; ++rnd) {
        int idx = rnd * 256 + tid;
        int r = idx >> 5, c = idx & 31;
        bf16x8 v = *(const bf16x8*)(Ab + r * 256 + c * 8);
        *(bf16x8*)((char*)Xs + swz(r, c * 16)) = v;
    }
    __syncthreads();

    f32x4 acc[4][4];

    // ================= stage A: H1 = gelu(X @ W1[:, :256]^T + b1 + msgc) ====
    #pragma unroll
    for (int mt = 0; mt < 4; ++mt)
        #pragma unroll
        for (int nt = 0; nt < 4; ++nt) {
            f32x4 z = {0.f, 0.f, 0.f, 0.f};
            acc[mt][nt] = z;
        }
    {
        const unsigned short* wr[4];
        #pragma unroll
        for (int nt = 0; nt < 4; ++nt) wr[nt] = W1 + (long)(n0w + nt * 16 + l15) * 512;
        #pragma unroll 4
        for (int ks = 0; ks < 8; ++ks) {
            int ko = ks * 32;
            bf16x8 af[4], bfr[4];
            #pragma unroll
            for (int mt = 0; mt < 4; ++mt)
                af[mt] = *(const bf16x8*)((const char*)Xs +
                         swz(mt * 16 + l15, (ko + q * 8) * 2));
            #pragma unroll
            for (int nt = 0; nt < 4; ++nt)
                bfr[nt] = *(const bf16x8*)(wr[nt] + ko + q * 8);
            #pragma unroll
            for (int mt = 0; mt < 4; ++mt)
                #pragma unroll
                for (int nt = 0; nt < 4; ++nt)
                    acc[mt][nt] = __builtin_amdgcn_mfma_f32_16x16x32_bf16(
                        af[mt], bfr[nt], acc[mt][nt], 0, 0, 0);
        }
        float bb[4];
        #pragma unroll
        for (int nt = 0; nt < 4; ++nt) bb[nt] = su_b1v[n0w + nt * 16 + l15];
        #pragma unroll
        for (int mt = 0; mt < 4; ++mt) {
            #pragma unroll
            for (int reg = 0; reg < 4; ++reg) {
                int lr = mt * 16 + q * 4 + reg;
                int p = m0 + lr;
                const float* mrow = msgc + ((long)b * 256 + p) * 256;
                bool hasm = (p < 256);
                #pragma unroll
                for (int nt = 0; nt < 4; ++nt) {
                    int gc = n0w + nt * 16 + l15;
                    float v = acc[mt][nt][reg] + bb[nt];
                    if (hasm) v += mrow[gc];
                    *(unsigned short*)((char*)Hs + swz(lr, gc * 2)) = f2bf(gelu_f(v));
                }
            }
        }
    }
    __syncthreads();

    // ================= stage B: NH = LN(H1 @ W2^T + b2) =====================
    #pragma unroll
    for (int mt = 0; mt < 4; ++mt)
        #pragma unroll
        for (int nt = 0; nt < 4; ++nt) {
            f32x4 z = {0.f, 0.f, 0.f, 0.f};
            acc[mt][nt] = z;
        }
    {
        const unsigned short* wr[4];
        #pragma unroll
        for (int nt = 0; nt < 4; ++nt) wr[nt] = W2 + (long)(n0w + nt * 16 + l15) * 256;
        #pragma unroll
        for (int ks = 0; ks < 8; ++ks) {
            int ko = ks * 32;
            bf16x8 af[4], bfr[4];
            #pragma unroll
            for (int mt = 0; mt < 4; ++mt) {
                int r = mt * 16 + l15;
                af[mt] = *(const bf16x8*)((const char*)Hs + swz(r, (ko + q * 8) * 2));
            }
            #pragma unroll
            for (int nt = 0; nt < 4; ++nt)
                bfr[nt] = *(const bf16x8*)(wr[nt] + ko + q * 8);
            #pragma unroll
            for (int mt = 0; mt < 4; ++mt)
                #pragma unroll
                for (int nt = 0; nt < 4; ++nt)
                    acc[mt][nt] = __builtin_amdgcn_mfma_f32_16x16x32_bf16(
                        af[mt], bfr[nt], acc[mt][nt], 0, 0, 0);
        }
        float bb[4], gg[4], eb[4];
        #pragma unroll
        for (int nt = 0; nt < 4; ++nt) {
            int gc = n0w + nt * 16 + l15;
            bb[nt] = su_b2v[gc]; gg[nt] = lng[gc]; eb[nt] = lnb[gc];
        }
        #pragma unroll
        for (int mt = 0; mt < 4; ++mt)
            #pragma unroll
            for (int nt = 0; nt < 4; ++nt)
                #pragma unroll
                for (int reg = 0; reg < 4; ++reg)
                    acc[mt][nt][reg] += bb[nt];
        #pragma unroll
        for (int mt = 0; mt < 4; ++mt) {
            #pragma unroll
            for (int reg = 0; reg < 4; ++reg) {
                float s = 0.f, s2 = 0.f;
                #pragma unroll
                for (int nt = 0; nt < 4; ++nt) {
                    float v = acc[mt][nt][reg];
                    s += v; s2 += v * v;
                }
                #pragma unroll
                for (int off = 1; off <= 8; off <<= 1) {
                    s += __shfl_xor(s, off);
                    s2 += __shfl_xor(s2, off);
                }
                if (l15 == 0) {
                    int row = mt * 16 + q * 4 + reg;
                    rsum[wid][row] = s; rsq[wid][row] = s2;
                }
            }
        }
        __syncthreads();   // all waves past MFMA loop -> Hs reads complete
        if (tid < 64) {
            float s = rsum[0][tid] + rsum[1][tid] + rsum[2][tid] + rsum[3][tid];
            float s2 = rsq[0][tid] + rsq[1][tid] + rsq[2][tid] + rsq[3][tid];
            float mu = s * (1.f / 256.f);
            float var = s2 * (1.f / 256.f) - mu * mu;
            rmu[tid] = mu;
            rrs[tid] = rsqrtf(var + 1e-5f);
        }
        __syncthreads();
        #pragma unroll
        for (int mt = 0; mt < 4; ++mt) {
            #pragma unroll
            for (int reg = 0; reg < 4; ++reg) {
                int lr = mt * 16 + q * 4 + reg;
                float mu = rmu[lr], rs = rrs[lr];
                #pragma unroll
                for (int nt = 0; nt < 4; ++nt) {
                    int gc = n0w + nt * 16 + l15;
                    unsigned short ov =
                        f2bf((acc[mt][nt][reg] - mu) * rs * gg[nt] + eb[nt]);
                    *(unsigned short*)((char*)Hs + swz(lr, gc * 2)) = ov; // stage C
                }
            }
        }
    }
    __syncthreads();

    // ---- coalesced NH writeback from LDS ----
    #pragma unroll
    for (int rnd = 0; rnd < 8; ++rnd) {
        int idx = rnd * 256 + tid;
        int r = idx >> 5, c = idx & 31;
        bf16x8 v = *(const bf16x8*)((const char*)Hs + swz(r, c * 16));
        *(bf16x8*)(NHb + ((long)b * CMAX + m0 + r) * 256 + c * 8) = v;
    }

    // ================= stage C: au gate over [X, NH] (K=512) ================
    #pragma unroll
    for (int mt = 0; mt < 4; ++mt)
        #pragma unroll
        for (int nt = 0; nt < 4; ++nt) {
            f32x4 z = {0.f, 0.f, 0.f, 0.f};
            acc[mt][nt] = z;
        }
    {
        const unsigned short* wr[4];
        #pragma unroll
        for (int nt = 0; nt < 4; ++nt) wr[nt] = WA + (long)(n0w + nt * 16 + l15) * 512;
        #pragma unroll 4
        for (int ks = 0; ks < 8; ++ks) {         // K 0..255: original X (LDS)
            int ko = ks * 32;
            bf16x8 af[4], bfr[4];
            #pragma unroll
            for (int mt = 0; mt < 4; ++mt)
                af[mt] = *(const bf16x8*)((const char*)Xs +
                         swz(mt * 16 + l15, (ko + q * 8) * 2));
            #pragma unroll
            for (int nt = 0; nt < 4; ++nt)
                bfr[nt] = *(const bf16x8*)(wr[nt] + ko + q * 8);
            #pragma unroll
            for (int mt = 0; mt < 4; ++mt)
                #pragma unroll
                for (int nt = 0; nt < 4; ++nt)
                    acc[mt][nt] = __builtin_amdgcn_mfma_f32_16x16x32_bf16(
                        af[mt], bfr[nt], acc[mt][nt], 0, 0, 0);
        }
        #pragma unroll
        for (int ks = 0; ks < 8; ++ks) {         // K 256..511: NH (LDS)
            int ko = ks * 32;
            int kw = 256 + ks * 32;
            bf16x8 af[4], bfr[4];
            #pragma unroll
            for (int mt = 0; mt < 4; ++mt) {
                int r = mt * 16 + l15;
                af[mt] = *(const bf16x8*)((const char*)Hs + swz(r, (ko + q * 8) * 2));
            }
            #pragma unroll
            for (int nt = 0; nt < 4; ++nt)
                bfr[nt] = *(const bf16x8*)(wr[nt] + kw + q * 8);
            #pragma unroll
            for (int mt = 0; mt < 4; ++mt)
                #pragma unroll
                for (int nt = 0; nt < 4; ++nt)
                    acc[mt][nt] = __builtin_amdgcn_mfma_f32_16x16x32_bf16(
                        af[mt], bfr[nt], acc[mt][nt], 0, 0, 0);
        }
        float bb[4], ww[4];
        #pragma unroll
        for (int nt = 0; nt < 4; ++nt) {
            int gc = n0w + nt * 16 + l15;
            bb[nt] = au_b1v[gc]; ww[nt] = w2v[gc];
        }
        #pragma unroll
        for (int mt = 0; mt < 4; ++mt) {
            #pragma unroll
            for (int reg = 0; reg < 4; ++reg) {
                float s = 0.f;
                #pragma unroll
                for (int nt = 0; nt < 4; ++nt)
                    s += gelu_f(acc[mt][nt][reg] + bb[nt]) * ww[nt];
                #pragma unroll
                for (int off = 1; off <= 8; off <<= 1) s += __shfl_xor(s, off);
                if (l15 == 0) rsum[wid][mt * 16 + q * 4 + reg] = s;
            }
        }
        __syncthreads();
        if (tid < 64) {
            int p = m0 + tid;
            if (p < C) {
                float z = rsum[0][tid] + rsum[1][tid] + rsum[2][tid] + rsum[3][tid] + b2s[0];
                float delta = 1.f / (1.f + expf(-z));
                float na = 0.7f * svals[b * 4096 + p] + 0.3f * delta;
                nac[(long)b * CMAX + p] = fminf(fmaxf(na, 0.f), 1.f);
            }
        }
    }
}

// ---------------- selectT + bandlist fused: one block per batch --------------
// Phase 1: rank-256 value via binary search (shfl reduce). Phase 2: compact
// band rows (|na - T| < BAND_EPS) into bandl via in-block atomic slots (order
// varies, harmless: bandfix does keyed per-row writes). Writes bandcnt[b]
// directly (no pre-zero memset needed).
__global__ void __launch_bounds__(256) selband_k(const float* __restrict__ nac,
        const int* __restrict__ cnt, float* __restrict__ T,
        int* __restrict__ bandl, int* __restrict__ bandcnt)
{
    __shared__ float v[CMAX];
    __shared__ int cs[4];
    __shared__ int sBand;
    int b = blockIdx.x, tid = threadIdx.x;
    int wid = tid >> 6, lane = tid & 63;
    int C = min(cnt[b], CMAX);
    for (int i = tid; i < CMAX; i += 256)
        v[i] = (i < C) ? nac[(long)b * CMAX + i] : -1.f;
    if (tid == 0) sBand = 0;
    __syncthreads();
    float lo = 0.f, hi = 1.f;
    for (int it = 0; it < 20; ++it) {   // 1e-6 resolution << BAND_EPS
        float mid = 0.5f * (lo + hi);
        int c = 0;
        for (int i = tid; i < CMAX; i += 256) c += (v[i] >= mid) ? 1 : 0;
        #pragma unroll
        for (int off = 32; off >= 1; off >>= 1) c += __shfl_xor(c, off);
        if (lane == 0) cs[wid] = c;
        __syncthreads();
        int tot = cs[0] + cs[1] + cs[2] + cs[3];
        __syncthreads();
        if (tot >= 256) lo = mid; else hi = mid;   // uniform across threads
    }
    if (tid == 0) T[b] = lo;
    // ---- band compaction (v[] still holds nac; exclude padding -1 rows) ----
    for (int i = tid; i < C; i += 256) {
        if (fabsf(v[i] - lo) < BAND_EPS) {
            int slot = atomicAdd(&sBand, 1);
            if (slot < MAXBAND) bandl[b * MAXBAND + slot] = i;
        }
    }
    __syncthreads();
    if (tid == 0) bandcnt[b] = min(sBand, MAXBAND);
}

// ---------------- fp32 recompute: 4 band rows per block, float4-packed W^T ---
__global__ void __launch_bounds__(256) bandfix_k(
    const float* __restrict__ hid, const int* __restrict__ sidx,
    const float* __restrict__ msgc,
    const float* __restrict__ w1Pf, const float* __restrict__ su_b1,
    const float* __restrict__ w2Pf, const float* __restrict__ su_b2,
    const float* __restrict__ ln_g, const float* __restrict__ ln_b,
    const float* __restrict__ auPf, const float* __restrict__ au_b1,
    const float* __restrict__ au_w2, const float* __restrict__ au_b2,
    const float* __restrict__ svals,
    const int* __restrict__ bandlist, const int* __restrict__ bandcnt,
    float* __restrict__ nac, unsigned short* __restrict__ NHb)
{
    int b = blockIdx.y;
    int M = min(bandcnt[b], MAXBAND);
    int base = blockIdx.x * 4;
    if (base >= M) return;
    int nact = min(M - base, 4);
    int tid = threadIdx.x;
    int wid = tid >> 6, lane = tid & 63;
    const float4* w1P = (const float4*)w1Pf;
    const float4* w2P = (const float4*)w2Pf;
    const float4* auP = (const float4*)auPf;
    __shared__ float xr[4][256];
    __shared__ float hy[4][256];
    __shared__ float nh[4][256];
    __shared__ float muS[4], rsS[4];
    __shared__ int ppS[4];
    if (tid < 4)
        ppS[tid] = (tid < nact) ? bandlist[b * MAXBAND + base + tid] : -1;
    __syncthreads();
    #pragma unroll
    for (int r = 0; r < 4; ++r) {
        int pp = ppS[r];
        xr[r][tid] = (pp >= 0) ? hid[((long)b * 4096 + sidx[b * 4096 + pp]) * 256 + tid] : 0.f;
    }
    __syncthreads();
    int n = tid;
    float acc[4];
    // ---- su1 ----
    #pragma unroll
    for (int r = 0; r < 4; ++r) acc[r] = 0.f;
    for (int k4 = 0; k4 < 64; ++k4) {
        float4 w = w1P[k4 * 256 + n];
        #pragma unroll
        for (int r = 0; r < 4; ++r) {
            float4 xv = *(const float4*)&xr[r][k4 * 4];
            acc[r] = fmaf(w.x, xv.x, acc[r]);
            acc[r] = fmaf(w.y, xv.y, acc[r]);
            acc[r] = fmaf(w.z, xv.z, acc[r]);
            acc[r] = fmaf(w.w, xv.w, acc[r]);
        }
    }
    float b1v = su_b1[n];
    #pragma unroll
    for (int r = 0; r < 4; ++r) {
        int pp = ppS[r];
        float s = acc[r] + b1v;
        if (pp >= 0 && pp < 256) s += msgc[((long)b * 256 + pp) * 256 + n];
        acc[r] = gelu_f(s);
    }
    __syncthreads();
    #pragma unroll
    for (int r = 0; r < 4; ++r) hy[r][n] = acc[r];
    __syncthreads();
    // ---- su2 ----
    #pragma unroll
    for (int r = 0; r < 4; ++r) acc[r] = 0.f;
    for (int k4 = 0; k4 < 64; ++k4) {
        float4 w = w2P[k4 * 256 + n];
        #pragma unroll
        for (int r = 0; r < 4; ++r) {
            float4 hv = *(const float4*)&hy[r][k4 * 4];
            acc[r] = fmaf(w.x, hv.x, acc[r]);
            acc[r] = fmaf(w.y, hv.y, acc[r]);
            acc[r] = fmaf(w.z, hv.z, acc[r]);
            acc[r] = fmaf(w.w, hv.w, acc[r]);
        }
    }
    __syncthreads();
    float b2v = su_b2[n];
    #pragma unroll
    for (int r = 0; r < 4; ++r) hy[r][n] = acc[r] + b2v;
    __syncthreads();
    // LN stats: wave wid handles row wid
    {
        int r = wid;
        float4 yv = *(const float4*)&hy[r][lane * 4];
        float s = yv.x + yv.y + yv.z + yv.w;
        float s2 = yv.x * yv.x + yv.y * yv.y + yv.z * yv.z + yv.w * yv.w;
        #pragma unroll
        for (int off = 32; off >= 1; off >>= 1) {
            s += __shfl_xor(s, off);
            s2 += __shfl_xor(s2, off);
        }
        if (lane == 0) {
            float mu = s * (1.f / 256.f);
            float var = s2 * (1.f / 256.f) - mu * mu;
            muS[r] = mu; rsS[r] = rsqrtf(var + 1e-5f);
        }
    }
    __syncthreads();
    float gv = ln_g[n], ev = ln_b[n];
    #pragma unroll
    for (int r = 0; r < 4; ++r) {
        float o = (hy[r][n] - muS[r]) * rsS[r] * gv + ev;
        nh[r][n] = o;
        if (ppS[r] >= 0) NHb[((long)b * CMAX + ppS[r]) * 256 + n] = f2bf(o);
    }
    __syncthreads();
    // ---- au ----
    #pragma unroll
    for (int r = 0; r < 4; ++r) acc[r] = 0.f;
    for (int k4 = 0; k4 < 64; ++k4) {
        float4 w = auP[k4 * 256 + n];
        #pragma unroll
        for (int r = 0; r < 4; ++r) {
            float4 xv = *(const float4*)&xr[r][k4 * 4];
            acc[r] = fmaf(w.x, xv.x, acc[r]);
            acc[r] = fmaf(w.y, xv.y, acc[r]);
            acc[r] = fmaf(w.z, xv.z, acc[r]);
            acc[r] = fmaf(w.w, xv.w, acc[r]);
        }
    }
    for (int k4 = 64; k4 < 128; ++k4) {
        float4 w = auP[k4 * 256 + n];
        #pragma unroll
        for (int r = 0; r < 4; ++r) {
            float4 hv = *(const float4*)&nh[r][(k4 - 64) * 4];
            acc[r] = fmaf(w.x, hv.x, acc[r]);
            acc[r] = fmaf(w.y, hv.y, acc[r]);
            acc[r] = fmaf(w.z, hv.z, acc[r]);
            acc[r] = fmaf(w.w, hv.w, acc[r]);
        }
    }
    float ab = au_b1[n], wv2 = au_w2[n];
    __syncthreads();
    #pragma unroll
    for (int r = 0; r < 4; ++r) hy[r][n] = gelu_f(acc[r] + ab) * wv2;
    __syncthreads();
    {
        int r = wid;
        float4 gvv = *(const float4*)&hy[r][lane * 4];
        float s = gvv.x + gvv.y + gvv.z + gvv.w;
        #pragma unroll
        for (int off = 32; off >= 1; off >>= 1) s += __shfl_xor(s, off);
        if (lane == 0 && ppS[r] >= 0) {
            float z = s + au_b2[0];
            float delta = 1.f / (1.f + expf(-z));
            float na = 0.7f * svals[b * 4096 + ppS[r]] + 0.3f * delta;
            nac[(long)b * CMAX + ppS[r]] = fminf(fmaxf(na, 0.f), 1.f);
        }
    }
}

// ---------------- scatter outputs ----------------
__global__ void __launch_bounds__(64) scatter_k(const float* __restrict__ selv,
        const int* __restrict__ selo, const int* __restrict__ selp,
        const unsigned short* __restrict__ NHb, float* __restrict__ out)
{
    int b = blockIdx.x >> 8, j = blockIdx.x & 255, t = threadIdx.x;
    int orig = selo[b * 256 + j];
    int p = selp[b * 256 + j];
    if (t == 0) out[b * 4096 + orig] = selv[b * 256 + j];
    const ushort4* src = (const ushort4*)(NHb + ((long)b * CMAX + p) * 256);
    ushort4 s = src[t];
    float4 o = make_float4(bf2f(s.x), bf2f(s.y), bf2f(s.z), bf2f(s.w));
    *(float4*)(out + 131072 + ((long)(b * 4096 + orig)) * 256 + t * 4) = o;
}

extern "C" void kernel_launch(void* const* d_in, const int* in_sizes, int n_in,
                              void* d_out, int out_size, void* d_ws, size_t ws_size,
                              hipStream_t stream)
{
    const float* act   = (const float*)d_in[0];
    const float* hid   = (const float*)d_in[1];
    const float* wi    = (const float*)d_in[2];
    const float* bi    = (const float*)d_in[3];
    const float* wo    = (const float*)d_in[4];
    const float* bo    = (const float*)d_in[5];
    const float* su_w1 = (const float*)d_in[6];
    const float* su_b1 = (const float*)d_in[7];
    const float* su_w2 = (const float*)d_in[8];
    const float* su_b2 = (const float*)d_in[9];
    const float* au_w1 = (const float*)d_in[10];
    const float* au_b1 = (const float*)d_in[11];
    const float* au_w2 = (const float*)d_in[12];
    const float* au_b2 = (const float*)d_in[13];
    const float* ln_g  = (const float*)d_in[14];
    const float* ln_b  = (const float*)d_in[15];
    float* out = (float*)d_out;

    char* ws = (char*)d_ws;
    size_t off = 0;
    auto alloc = [&](size_t bytes) {
        size_t o = off; off += (bytes + 255) & ~(size_t)255; return o;
    };
    float* svals = (float*)(ws + alloc((size_t)32 * 4096 * 4));
    int*   sidx  = (int*)  (ws + alloc((size_t)32 * 4096 * 4));
    int*   cnt   = (int*)  (ws + alloc(256));
    float* qkv   = (float*)(ws + alloc((size_t)32 * 256 * 768 * 4));
    float* Sb    = (float*)(ws + alloc((size_t)32 * 4 * 256 * 256 * 4));
    float* Ob    = (float*)(ws + alloc((size_t)32 * 256 * 256 * 4));
    float* MSGC  = (float*)(ws + alloc((size_t)32 * 256 * 256 * 4));
    float* selv  = (float*)(ws + alloc((size_t)32 * 256 * 4));
    int*   selo  = (int*)  (ws + alloc((size_t)32 * 256 * 4));
    int*   selp  = (int*)  (ws + alloc((size_t)32 * 256 * 4));
    unsigned short* swb1 = (unsigned short*)(ws + alloc((size_t)256 * 512 * 2));
    unsigned short* swb2 = (unsigned short*)(ws + alloc((size_t)256 * 256 * 2));
    unsigned short* awb1 = (unsigned short*)(ws + alloc((size_t)256 * 512 * 2));
    float* w1P = (float*)(ws + alloc((size_t)256 * 256 * 4));
    float* w2P = (float*)(ws + alloc((size_t)256 * 256 * 4));
    float* auP = (float*)(ws + alloc((size_t)512 * 256 * 4));
    unsigned short* Xb   = (unsigned short*)(ws + alloc((size_t)32 * CMAX * 256 * 2));
    unsigned short* NHb  = (unsigned short*)(ws + alloc((size_t)32 * CMAX * 256 * 2));
    float* nac = (float*)(ws + alloc((size_t)32 * CMAX * 4));
    float* Tb  = (float*)(ws + alloc(128));
    int* bandl = (int*)(ws + alloc((size_t)32 * MAXBAND * 4));
    int* bandc = (int*)(ws + alloc(128));

    // 1. front: zero outputs + deterministic topk1 + weight prep (one launch)
    front_k<<<2848, 256, 0, stream>>>((float4*)out, (long)out_size / 4,
        act, svals, sidx, cnt, su_w1, su_w2, au_w1, swb1, swb2, awb1,
        w1P, w2P, auP);
    // 2. gather + bf16 candidate rows
    gatherX_k<<<dim3(CMAX / 4, 32), 256, 0, stream>>>(hid, sidx, cnt, Xb);
    // 3. qkv = gather(hidden) @ wi^T + bi  (64x128 tiles -> 768 blocks)
    gemm_k<64, 128, 8, 4, true, true, 1><<<dim3(6, 4, 32), 256, 0, stream>>>(
        hid, 256, (long)4096 * 256, 0, 1,
        wi, 256, 0, 0, 1,
        qkv, 768, (long)256 * 768, 0, 1,
        256, bi, nullptr, 0, sidx, 4096, 0.f);
    // 4. P = softmax(q @ k^T / 8)  (32x256 tiles -> 1024 blocks, EPI=4)
    gemm_k<32, 256, 4, 8, true, false, 4><<<dim3(1, 8, 128), 256, 0, stream>>>(
        qkv, 768, 196608, 64, 4,
        qkv + 256, 768, 196608, 64, 4,
        Sb, 256, 65536, 0, 1,
        64, nullptr, nullptr, 0, nullptr, 0, 0.125f);
    // 5. O = P @ V
    gemm_k<64, 64, 4, 4, false, false, 0><<<dim3(1, 4, 128), 256, 0, stream>>>(
        Sb, 256, 65536, 0, 1,
        qkv + 512, 768, 196608, 64, 4,
        Ob, 256, 65536, 64, 4,
        256, nullptr, nullptr, 0, nullptr, 0, 0.f);
    // 6. MSGC = ((O @ wo^T + bo) * tv) @ W1b^T  -- fused
    msgc_k<<<dim3(8, 32), 256, 0, stream>>>(Ob, wo, bo, su_w1, svals, MSGC);
    // 7. fused candidate-row MLP (su1 -> su2+LN -> au), bf16 MFMA + LDS
    fused_mlp_k<<<dim3(CMAX / 64, 32), 256, 0, stream>>>(Xb, swb1, swb2, awb1,
        su_b1, MSGC, su_b2, ln_g, ln_b, au_b1, au_w2, au_b2, svals, cnt,
        NHb, nac);
    // 8. rank-256 value + band compaction (fused, one block per batch)
    selband_k<<<32, 256, 0, stream>>>(nac, cnt, Tb, bandl, bandc);
    // 9. fp32 recompute of boundary-band rows, 4 rows/block, packed W^T
    bandfix_k<<<dim3(MAXBAND / 4, 32), 256, 0, stream>>>(hid, sidx, MSGC,
        w1P, su_b1, w2P, su_b2, ln_g, ln_b, auP, au_b1, au_w2, au_b2,
        svals, bandl, bandc, nac, NHb);
    // 10. exact top-256 selection over corrected new activations
    topk2_k<<<32, 256, 0, stream>>>(nac, sidx, cnt, selv, selo, selp);
    // 11. scatter selected rows
    scatter_k<<<8192, 64, 0, stream>>>(selv, selo, selp, NHb, out);
}